// Round 2
// baseline (762.646 us; speedup 1.0000x reference)
//
#include <hip/hip_runtime.h>
#include <hip/hip_bf16.h>

typedef __attribute__((ext_vector_type(8))) short bf16x8;
typedef __attribute__((ext_vector_type(4))) float f32x4;

__device__ __forceinline__ unsigned short f2bf(float f){
  __hip_bfloat16 h = __float2bfloat16(f);
  return *reinterpret_cast<unsigned short*>(&h);
}

#define GLDS16(gptr, lptr) \
  __builtin_amdgcn_global_load_lds((const __attribute__((address_space(1))) unsigned int*)(gptr), \
                                   (__attribute__((address_space(3))) unsigned int*)(lptr), 16, 0, 0)

// ---------------- small prep kernels ----------------
__global__ void cvtk(const float* __restrict__ s, unsigned short* __restrict__ d, int n){
  int i = blockIdx.x*256 + threadIdx.x;
  if (i < n) d[i] = f2bf(s[i]);
}

__global__ void biask(const int* __restrict__ ri, const float* __restrict__ tbl, float* __restrict__ out){
  int g = blockIdx.x*256 + threadIdx.x;
  if (g < 8*9604){
    int h = g / 9604, ij = g % 9604;
    out[g] = tbl[ri[ij]*8 + h];
  }
}

// zero the pad columns (98..127) of vT rows: 512*8*32 rows, 15 uints each
__global__ void padzk(unsigned int* __restrict__ vT){
  int idx = blockIdx.x*256 + threadIdx.x;
  if (idx < 131072*15){
    int row = idx / 15, c = idx % 15;
    vT[row*64 + 49 + c] = 0u;
  }
}

// ---------------- LayerNorm (+optional shift/window map) ----------------
// mode 0: read x at shifted coords for GLOBAL token (tokbase+local), write windowed order at LOCAL index
// mode 1: identity token map (LN2), tokbase=0
__launch_bounds__(256)
__global__ void lnk(const float* __restrict__ xin, const float* __restrict__ gw, const float* __restrict__ gb,
                    unsigned short* __restrict__ hout, int mode, int tokbase)
{
  int wid = threadIdx.x >> 6, lane = threadIdx.x & 63;
  int tokl = blockIdx.x*4 + wid;
  int src;
  if (mode == 0){
    int tok = tokbase + tokl;
    int w = tok / 98, n = tok % 98;
    int b = w >> 9, rr = w & 511;
    int di = rr >> 6, hi = (rr >> 3) & 7, wi = rr & 7;
    int d2 = n / 49, n2 = n % 49, h2 = n2 / 7, w2 = n2 % 7;
    int sd = (di*2 + d2 + 1) & 15;
    int sh = hi*7 + h2 + 3; if (sh >= 56) sh -= 56;
    int sw = wi*7 + w2 + 3; if (sw >= 56) sw -= 56;
    src = ((b*16 + sd)*56 + sh)*56 + sw;
  } else {
    src = tokl;
  }
  float4 v = *(const float4*)(xin + (size_t)src*256 + lane*4);
  float s  = v.x + v.y + v.z + v.w;
  float s2 = v.x*v.x + v.y*v.y + v.z*v.z + v.w*v.w;
  #pragma unroll
  for (int off = 1; off < 64; off <<= 1){
    s  += __shfl_xor(s, off);
    s2 += __shfl_xor(s2, off);
  }
  float mean = s * (1.f/256.f);
  float var  = s2 * (1.f/256.f) - mean*mean;
  float rstd = rsqrtf(var + 1e-5f);
  int c = lane*4;
  float4 wv = *(const float4*)(gw + c);
  float4 bv = *(const float4*)(gb + c);
  unsigned int p0 = (unsigned int)f2bf((v.x-mean)*rstd*wv.x + bv.x)
                  | ((unsigned int)f2bf((v.y-mean)*rstd*wv.y + bv.y) << 16);
  unsigned int p1 = (unsigned int)f2bf((v.z-mean)*rstd*wv.z + bv.z)
                  | ((unsigned int)f2bf((v.w-mean)*rstd*wv.w + bv.w) << 16);
  uint2 pk; pk.x = p0; pk.y = p1;
  *(uint2*)(hout + (size_t)tokl*256 + c) = pk;
}

// ---------------- bf16 MFMA GEMM: C[M,N] = A[M,K] * Bw[N,K]^T + bias ----------------
// EPI 0: qkv -> q,k plain [row][512]; v transposed into vT[wl][h][e][128]
// EPI 1: proj + unwindow/unroll + residual (row offset moff)
// EPI 2: fc1 + GELU(erf) -> bf16 [row][1024]
// EPI 3: fc2 accumulate into d_out at row moff+row
template<int EPI>
__launch_bounds__(256, 2)
__global__ void gemmk(const unsigned short* __restrict__ A, const unsigned short* __restrict__ Bw,
                      const float* __restrict__ bias, int K, int nbx,
                      unsigned short* __restrict__ outb, const float* __restrict__ xres,
                      float* __restrict__ outf, int moff, unsigned short* __restrict__ vTp)
{
  __shared__ unsigned short As[128*32];
  __shared__ unsigned short Bs[128*32];
  int tid = threadIdx.x;
  int wid = tid >> 6, lane = tid & 63, l16 = lane & 15, lk = lane >> 4;
  int wm = wid >> 1, wn = wid & 1;
  int mblk = blockIdx.x / nbx, nblk = blockIdx.x % nbx;
  const unsigned short* Ab = A  + (size_t)mblk*128*K;
  const unsigned short* Bb = Bw + (size_t)nblk*128*K;
  int rA = tid >> 2, kcA = (tid & 3)*8;

  f32x4 acc[4][4];
  #pragma unroll
  for (int i = 0; i < 4; i++)
    #pragma unroll
    for (int j = 0; j < 4; j++)
      acc[i][j] = (f32x4){0.f,0.f,0.f,0.f};

  for (int ks = 0; ks < K; ks += 32){
    __syncthreads();
    GLDS16(Ab + (size_t)rA*K      + ks + kcA, &As[wid*512]);
    GLDS16(Ab + (size_t)(rA+64)*K + ks + kcA, &As[2048 + wid*512]);
    GLDS16(Bb + (size_t)rA*K      + ks + kcA, &Bs[wid*512]);
    GLDS16(Bb + (size_t)(rA+64)*K + ks + kcA, &Bs[2048 + wid*512]);
    __syncthreads();
    bf16x8 af[4], bfr[4];
    #pragma unroll
    for (int mi = 0; mi < 4; mi++) af[mi]  = *(const bf16x8*)&As[(wm*64 + mi*16 + l16)*32 + lk*8];
    #pragma unroll
    for (int ni = 0; ni < 4; ni++) bfr[ni] = *(const bf16x8*)&Bs[(wn*64 + ni*16 + l16)*32 + lk*8];
    #pragma unroll
    for (int mi = 0; mi < 4; mi++)
      #pragma unroll
      for (int ni = 0; ni < 4; ni++)
        acc[mi][ni] = __builtin_amdgcn_mfma_f32_16x16x32_bf16(af[mi], bfr[ni], acc[mi][ni], 0, 0, 0);
  }

  int rowb = mblk*128 + wm*64;
  int colb = nblk*128 + wn*64;
  #pragma unroll
  for (int mi = 0; mi < 4; mi++){
    #pragma unroll
    for (int r = 0; r < 4; r++){
      int row = rowb + mi*16 + lk*4 + r;
      if constexpr (EPI == 0){
        if (colb < 512){
          #pragma unroll
          for (int ni = 0; ni < 4; ni++){
            int col = colb + ni*16 + l16;
            float v = acc[mi][ni][r] + bias[col];
            outb[(size_t)row*512 + col] = f2bf(v);
          }
        } else {
          int wl = row / 98, n = row % 98;
          #pragma unroll
          for (int ni = 0; ni < 4; ni++){
            int col = colb + ni*16 + l16;
            float v = acc[mi][ni][r] + bias[col];
            int head = (col >> 5) & 7, e = col & 31;
            vTp[(((size_t)wl*8 + head)*32 + e)*128 + n] = f2bf(v);
          }
        }
      } else if constexpr (EPI == 1){
        int grow = moff + row;
        int w = grow / 98, n = grow % 98;
        int b = w >> 9, rr = w & 511;
        int di = rr >> 6, hi = (rr >> 3) & 7, wi = rr & 7;
        int d2 = n / 49, n2 = n % 49, h2 = n2 / 7, w2 = n2 % 7;
        int sd = (di*2 + d2 + 1) & 15;
        int sh = hi*7 + h2 + 3; if (sh >= 56) sh -= 56;
        int sw = wi*7 + w2 + 3; if (sw >= 56) sw -= 56;
        size_t tnat = (((size_t)b*16 + sd)*56 + sh)*56 + sw;
        #pragma unroll
        for (int ni = 0; ni < 4; ni++){
          int col = colb + ni*16 + l16;
          float v = acc[mi][ni][r] + bias[col];
          outf[tnat*256 + col] = xres[tnat*256 + col] + v;
        }
      } else if constexpr (EPI == 2){
        #pragma unroll
        for (int ni = 0; ni < 4; ni++){
          int col = colb + ni*16 + l16;
          float v = acc[mi][ni][r] + bias[col];
          float gl = v * 0.5f * (1.f + erff(v * 0.70710678118654752f));
          outb[(size_t)row*1024 + col] = f2bf(gl);
        }
      } else {
        #pragma unroll
        for (int ni = 0; ni < 4; ni++){
          int col = colb + ni*16 + l16;
          float v = acc[mi][ni][r] + bias[col];
          outf[((size_t)(moff + row))*256 + col] += v;
        }
      }
    }
  }
}

// ---------------- fused window attention ----------------
// block = (window wl, m-tile mt); 4 waves x 2 heads each; mask tile staged in LDS.
// Q/K fragments read directly from plain qk [row][512]; V from vT[wl][h][e][128].
__launch_bounds__(256)
__global__ void attnk(const unsigned short* __restrict__ qk, const unsigned short* __restrict__ vT,
                      const float* __restrict__ biasf, const float* __restrict__ mask,
                      unsigned short* __restrict__ obuf)
{
  __shared__ float maskS[16][100];
  __shared__ unsigned short P[4][16*136];
  int tid = threadIdx.x, wid = tid >> 6, lane = tid & 63, l16 = lane & 15, lk = lane >> 4;
  int wl = blockIdx.x / 7, mt = blockIdx.x % 7;

  const float* mm = mask + (size_t)wl*9604;
  for (int idx = tid; idx < 1568; idx += 256){
    int i = idx / 98, j = idx - i*98;
    int gi = mt*16 + i; if (gi > 97) gi = 97;
    maskS[i][j] = mm[gi*98 + j];
  }
  unsigned short* Pw = &P[wid][0];
  { int rr = lane >> 2, cc = 112 + (lane & 3)*4;
    *(uint2*)&Pw[rr*136 + cc] = make_uint2(0u, 0u); }   // zero pad cols 112..127
  __syncthreads();

  int qrow = mt*16 + l16; if (qrow > 97) qrow = 97;

  #pragma unroll
  for (int hh = 0; hh < 2; hh++){
    int h = wid + hh*4;
    bf16x8 qa = *(const bf16x8*)(qk + (size_t)(wl*98 + qrow)*512 + h*32 + lk*8);
    f32x4 s[7];
    #pragma unroll
    for (int nt = 0; nt < 7; nt++){
      int kc = nt*16 + l16; if (kc > 97) kc = 97;
      bf16x8 kf = *(const bf16x8*)(qk + (size_t)(wl*98 + kc)*512 + 256 + h*32 + lk*8);
      f32x4 z = (f32x4){0.f,0.f,0.f,0.f};
      s[nt] = __builtin_amdgcn_mfma_f32_16x16x32_bf16(qa, kf, z, 0, 0, 0);
    }
    const float* bh = biasf + h*9604;
    float mx[4] = {-3e38f,-3e38f,-3e38f,-3e38f};
    #pragma unroll
    for (int r = 0; r < 4; r++){
      int it = lk*4 + r;
      int gi = mt*16 + it; if (gi > 97) gi = 97;
      #pragma unroll
      for (int nt = 0; nt < 7; nt++){
        int j = nt*16 + l16;
        float add = (j < 98) ? (bh[gi*98 + j] + maskS[it][j]) : -1e30f;
        float val = fmaf(s[nt][r], 0.17677669529663687f, add);
        s[nt][r] = val;
        mx[r] = fmaxf(mx[r], val);
      }
    }
    #pragma unroll
    for (int r = 0; r < 4; r++){
      #pragma unroll
      for (int off = 1; off < 16; off <<= 1) mx[r] = fmaxf(mx[r], __shfl_xor(mx[r], off));
    }
    float sm[4] = {0.f,0.f,0.f,0.f};
    #pragma unroll
    for (int r = 0; r < 4; r++){
      #pragma unroll
      for (int nt = 0; nt < 7; nt++){
        float e = __expf(s[nt][r] - mx[r]);
        s[nt][r] = e; sm[r] += e;
      }
    }
    #pragma unroll
    for (int r = 0; r < 4; r++){
      #pragma unroll
      for (int off = 1; off < 16; off <<= 1) sm[r] += __shfl_xor(sm[r], off);
      sm[r] = 1.f / sm[r];
    }
    #pragma unroll
    for (int r = 0; r < 4; r++)
      #pragma unroll
      for (int nt = 0; nt < 7; nt++)
        Pw[(lk*4 + r)*136 + nt*16 + l16] = f2bf(s[nt][r]*sm[r]);
    __syncthreads();

    const unsigned short* vtb = vT + (size_t)(wl*8 + h)*32*128;
    f32x4 o0 = (f32x4){0.f,0.f,0.f,0.f}, o1 = (f32x4){0.f,0.f,0.f,0.f};
    #pragma unroll
    for (int kcc = 0; kcc < 4; kcc++){
      bf16x8 pa = *(const bf16x8*)&Pw[l16*136 + kcc*32 + lk*8];
      bf16x8 v0 = *(const bf16x8*)(vtb + (size_t)l16*128      + kcc*32 + lk*8);
      bf16x8 v1 = *(const bf16x8*)(vtb + (size_t)(16+l16)*128 + kcc*32 + lk*8);
      o0 = __builtin_amdgcn_mfma_f32_16x16x32_bf16(pa, v0, o0, 0, 0, 0);
      o1 = __builtin_amdgcn_mfma_f32_16x16x32_bf16(pa, v1, o1, 0, 0, 0);
    }
    #pragma unroll
    for (int r = 0; r < 4; r++){
      int n = mt*16 + lk*4 + r;
      if (n < 98){
        size_t ob = ((size_t)wl*98 + n)*256 + h*32;
        obuf[ob + l16]      = f2bf(o0[r]);
        obuf[ob + 16 + l16] = f2bf(o1[r]);
      }
    }
    __syncthreads();
  }
}

extern "C" void kernel_launch(void* const* d_in, const int* in_sizes, int n_in,
                              void* d_out, int out_size, void* d_ws, size_t ws_size,
                              hipStream_t stream)
{
  const float* x     = (const float*)d_in[0];
  const float* maskm = (const float*)d_in[1];
  const int*   ri    = (const int*)d_in[2];
  const float* tbl   = (const float*)d_in[3];
  const float* n1w   = (const float*)d_in[4];
  const float* n1b   = (const float*)d_in[5];
  const float* qkvw  = (const float*)d_in[6];
  const float* qkvbv = (const float*)d_in[7];
  const float* projw = (const float*)d_in[8];
  const float* projb = (const float*)d_in[9];
  const float* n2w   = (const float*)d_in[10];
  const float* n2b   = (const float*)d_in[11];
  const float* fc1w  = (const float*)d_in[12];
  const float* fc1b  = (const float*)d_in[13];
  const float* fc2w  = (const float*)d_in[14];
  const float* fc2b  = (const float*)d_in[15];
  float* dout = (float*)d_out;
  char* ws = (char*)d_ws;

  // workspace layout (bytes); peak ~113 MB
  unsigned short* wq = (unsigned short*)(ws + 0);         // 768*256 bf16
  unsigned short* wp = (unsigned short*)(ws + 393216);    // 256*256 bf16
  unsigned short* w1 = (unsigned short*)(ws + 524288);    // 1024*256 bf16
  unsigned short* w2 = (unsigned short*)(ws + 1048576);   // 256*1024 bf16
  float* biasf       = (float*)(ws + 1572864);            // 8*9604 f32
  unsigned short* hb   = (unsigned short*)(ws + 2097152);   // chunk: 50176*256 bf16 (LN1 out, then attn out)
  unsigned short* qkO  = (unsigned short*)(ws + 27787264);  // chunk: 50176*512 bf16 (q,k plain)
  unsigned short* vT   = (unsigned short*)(ws + 79167488);  // chunk: 512*8*32*128 bf16
  // part 2 (after part 1 dead):
  unsigned short* h2 = (unsigned short*)(ws + 2097152);     // 100352*256 bf16
  unsigned short* g  = (unsigned short*)(ws + 53477376);    // 25088*1024 bf16

  cvtk<<<768, 256, 0, stream>>>(qkvw, wq, 196608);
  cvtk<<<256, 256, 0, stream>>>(projw, wp, 65536);
  cvtk<<<1024, 256, 0, stream>>>(fc1w, w1, 262144);
  cvtk<<<1024, 256, 0, stream>>>(fc2w, w2, 262144);
  biask<<<(76832 + 255)/256, 256, 0, stream>>>(ri, tbl, biasf);
  padzk<<<7680, 256, 0, stream>>>((unsigned int*)vT);

  for (int c = 0; c < 2; c++){
    int rowbase = c*50176;
    lnk<<<12544, 256, 0, stream>>>(x, n1w, n1b, hb, 0, rowbase);
    gemmk<0><<<392*6, 256, 0, stream>>>(hb, wq, qkvbv, 256, 6, qkO, nullptr, nullptr, 0, vT);
    attnk<<<512*7, 256, 0, stream>>>(qkO, vT, biasf, maskm, hb);
    gemmk<1><<<392*2, 256, 0, stream>>>(hb, wp, projb, 256, 2, nullptr, x, dout, rowbase, nullptr);
  }
  lnk<<<25088, 256, 0, stream>>>(dout, n2w, n2b, h2, 1, 0);
  for (int c = 0; c < 4; c++){
    gemmk<2><<<196*8, 256, 0, stream>>>(h2 + (size_t)c*25088*256, w1, fc1b, 256, 8, g, nullptr, nullptr, 0, nullptr);
    gemmk<3><<<196*2, 256, 0, stream>>>(g, w2, fc2b, 1024, 2, nullptr, nullptr, dout, c*25088, nullptr);
  }
}

// Round 3
// 574.516 us; speedup vs baseline: 1.3275x; 1.3275x over previous
//
#include <hip/hip_runtime.h>
#include <hip/hip_bf16.h>

typedef __attribute__((ext_vector_type(8))) short bf16x8;
typedef __attribute__((ext_vector_type(4))) float f32x4;

__device__ __forceinline__ unsigned short f2bf(float f){
  __hip_bfloat16 h = __float2bfloat16(f);
  return *reinterpret_cast<unsigned short*>(&h);
}
__device__ __forceinline__ float bf2f(unsigned short u){
  unsigned int v = ((unsigned int)u) << 16;
  return __uint_as_float(v);
}

#define GLDS16(gptr, lptr) \
  __builtin_amdgcn_global_load_lds((const __attribute__((address_space(1))) unsigned int*)(gptr), \
                                   (__attribute__((address_space(3))) unsigned int*)(lptr), 16, 0, 0)

// ---------------- small prep kernels ----------------
__global__ void cvtk(const float* __restrict__ s, unsigned short* __restrict__ d, int n){
  int i = blockIdx.x*256 + threadIdx.x;
  if (i < n) d[i] = f2bf(s[i]);
}

// combo[p][h][i][j] = rel_bias[h][i][j] + mask_pattern[p][i][j], bf16.
// p = boundary signature (di==7)<<2 | (hi==7)<<1 | (wi==7); representative window
// wrep = 64*(p&4?7:0) + 8*(p&2?7:0) + (p&1?7:0) has exactly that mask.
__global__ void combok(const int* __restrict__ ri, const float* __restrict__ tbl,
                       const float* __restrict__ mask, unsigned short* __restrict__ out){
  int g = blockIdx.x*256 + threadIdx.x;
  if (g < 8*8*9604){
    int ph = g / 9604, ij = g % 9604;
    int p = ph >> 3, h = ph & 7;
    int wrep = ((p&4)?448:0) + ((p&2)?56:0) + ((p&1)?7:0);
    float v = tbl[ri[ij]*8 + h] + mask[(size_t)wrep*9604 + ij];
    out[g] = f2bf(v);
  }
}

// ---------------- LayerNorm (+optional shift/window map) ----------------
__launch_bounds__(256)
__global__ void lnk(const float* __restrict__ xin, const float* __restrict__ gw, const float* __restrict__ gb,
                    unsigned short* __restrict__ hout, int mode)
{
  int wid = threadIdx.x >> 6, lane = threadIdx.x & 63;
  int tok = blockIdx.x*4 + wid;
  int src;
  if (mode == 0){
    int w = tok / 98, n = tok % 98;
    int b = w >> 9, rr = w & 511;
    int di = rr >> 6, hi = (rr >> 3) & 7, wi = rr & 7;
    int d2 = n / 49, n2 = n % 49, h2 = n2 / 7, w2 = n2 % 7;
    int sd = (di*2 + d2 + 1) & 15;
    int sh = hi*7 + h2 + 3; if (sh >= 56) sh -= 56;
    int sw = wi*7 + w2 + 3; if (sw >= 56) sw -= 56;
    src = ((b*16 + sd)*56 + sh)*56 + sw;
  } else {
    src = tok;
  }
  float4 v = *(const float4*)(xin + (size_t)src*256 + lane*4);
  float s  = v.x + v.y + v.z + v.w;
  float s2 = v.x*v.x + v.y*v.y + v.z*v.z + v.w*v.w;
  #pragma unroll
  for (int off = 1; off < 64; off <<= 1){
    s  += __shfl_xor(s, off);
    s2 += __shfl_xor(s2, off);
  }
  float mean = s * (1.f/256.f);
  float var  = s2 * (1.f/256.f) - mean*mean;
  float rstd = rsqrtf(var + 1e-5f);
  int c = lane*4;
  float4 wv = *(const float4*)(gw + c);
  float4 bv = *(const float4*)(gb + c);
  unsigned int p0 = (unsigned int)f2bf((v.x-mean)*rstd*wv.x + bv.x)
                  | ((unsigned int)f2bf((v.y-mean)*rstd*wv.y + bv.y) << 16);
  unsigned int p1 = (unsigned int)f2bf((v.z-mean)*rstd*wv.z + bv.z)
                  | ((unsigned int)f2bf((v.w-mean)*rstd*wv.w + bv.w) << 16);
  uint2 pk; pk.x = p0; pk.y = p1;
  *(uint2*)(hout + (size_t)tok*256 + c) = pk;
}

// ---------------- bf16 MFMA GEMM: C[M,N] = A[M,K] * Bw[N,K]^T + bias ----------------
// XCD-chunked bijective block swizzle (grid always divisible by 8).
// EPI 0: qkv scatter per-head (+q scale)   EPI 1: proj + unwindow/unroll + residual
// EPI 2: fc1 + GELU(erf) -> bf16           EPI 3: fc2 accumulate into d_out
template<int EPI>
__launch_bounds__(256, 2)
__global__ void gemmk(const unsigned short* __restrict__ A, const unsigned short* __restrict__ Bw,
                      const float* __restrict__ bias, int K, int nbx,
                      unsigned short* __restrict__ outb, const float* __restrict__ xres,
                      float* __restrict__ outf, int moff)
{
  __shared__ unsigned short As[128*32];
  __shared__ unsigned short Bs[128*32];
  int tid = threadIdx.x;
  int wid = tid >> 6, lane = tid & 63, l16 = lane & 15, lk = lane >> 4;
  int wm = wid >> 1, wn = wid & 1;
  int cpx = gridDim.x >> 3;
  int swb = (blockIdx.x & 7)*cpx + (blockIdx.x >> 3);
  int mblk = swb / nbx, nblk = swb % nbx;
  const unsigned short* Ab = A  + (size_t)mblk*128*K;
  const unsigned short* Bb = Bw + (size_t)nblk*128*K;
  int rA = tid >> 2, kcA = (tid & 3)*8;

  f32x4 acc[4][4];
  #pragma unroll
  for (int i = 0; i < 4; i++)
    #pragma unroll
    for (int j = 0; j < 4; j++)
      acc[i][j] = (f32x4){0.f,0.f,0.f,0.f};

  for (int ks = 0; ks < K; ks += 32){
    __syncthreads();
    GLDS16(Ab + (size_t)rA*K      + ks + kcA, &As[wid*512]);
    GLDS16(Ab + (size_t)(rA+64)*K + ks + kcA, &As[2048 + wid*512]);
    GLDS16(Bb + (size_t)rA*K      + ks + kcA, &Bs[wid*512]);
    GLDS16(Bb + (size_t)(rA+64)*K + ks + kcA, &Bs[2048 + wid*512]);
    __syncthreads();
    bf16x8 af[4], bfr[4];
    #pragma unroll
    for (int mi = 0; mi < 4; mi++) af[mi]  = *(const bf16x8*)&As[(wm*64 + mi*16 + l16)*32 + lk*8];
    #pragma unroll
    for (int ni = 0; ni < 4; ni++) bfr[ni] = *(const bf16x8*)&Bs[(wn*64 + ni*16 + l16)*32 + lk*8];
    #pragma unroll
    for (int mi = 0; mi < 4; mi++)
      #pragma unroll
      for (int ni = 0; ni < 4; ni++)
        acc[mi][ni] = __builtin_amdgcn_mfma_f32_16x16x32_bf16(af[mi], bfr[ni], acc[mi][ni], 0, 0, 0);
  }

  int rowb = mblk*128 + wm*64;
  int colb = nblk*128 + wn*64;
  #pragma unroll
  for (int mi = 0; mi < 4; mi++){
    #pragma unroll
    for (int r = 0; r < 4; r++){
      int row = rowb + mi*16 + lk*4 + r;
      if constexpr (EPI == 0){
        int w = row / 98, n = row % 98;
        size_t obase = ((size_t)w*8)*3136 + (size_t)n*32;
        #pragma unroll
        for (int ni = 0; ni < 4; ni++){
          int col = colb + ni*16 + l16;
          float v = acc[mi][ni][r] + bias[col];
          int which = col >> 8, head = (col >> 5) & 7, e = col & 31;
          if (which == 0) v *= 0.17677669529663687f;
          outb[(size_t)which*25690112 + obase + (size_t)head*3136 + e] = f2bf(v);
        }
      } else if constexpr (EPI == 1){
        int w = row / 98, n = row % 98;
        int b = w >> 9, rr = w & 511;
        int di = rr >> 6, hi = (rr >> 3) & 7, wi = rr & 7;
        int d2 = n / 49, n2 = n % 49, h2 = n2 / 7, w2 = n2 % 7;
        int sd = (di*2 + d2 + 1) & 15;
        int sh = hi*7 + h2 + 3; if (sh >= 56) sh -= 56;
        int sw = wi*7 + w2 + 3; if (sw >= 56) sw -= 56;
        size_t tnat = (((size_t)b*16 + sd)*56 + sh)*56 + sw;
        #pragma unroll
        for (int ni = 0; ni < 4; ni++){
          int col = colb + ni*16 + l16;
          float v = acc[mi][ni][r] + bias[col];
          outf[tnat*256 + col] = xres[tnat*256 + col] + v;
        }
      } else if constexpr (EPI == 2){
        #pragma unroll
        for (int ni = 0; ni < 4; ni++){
          int col = colb + ni*16 + l16;
          float v = acc[mi][ni][r] + bias[col];
          float gl = v * 0.5f * (1.f + erff(v * 0.70710678118654752f));
          outb[(size_t)row*1024 + col] = f2bf(gl);
        }
      } else {
        #pragma unroll
        for (int ni = 0; ni < 4; ni++){
          int col = colb + ni*16 + l16;
          float v = acc[mi][ni][r] + bias[col];
          outf[((size_t)(moff + row))*256 + col] += v;
        }
      }
    }
  }
}

// ---------------- fused window attention ----------------
// block = one (window, head): 4 waves share K/V via L1; wave handles mt = wid, wid+4.
// No block barriers (per-wave P regions; LDS ops are wave-ordered).
__launch_bounds__(256)
__global__ void attnk(const unsigned short* __restrict__ qkv, const unsigned short* __restrict__ combo,
                      unsigned short* __restrict__ obuf)
{
  __shared__ unsigned short P[4][16*136];   // stride 136 breaks the 256B-stride bank conflict
  int tid = threadIdx.x, wid = tid >> 6, lane = tid & 63, l16 = lane & 15, lk = lane >> 4;
  int cpx = gridDim.x >> 3;
  int swb = (blockIdx.x & 7)*cpx + (blockIdx.x >> 3);
  int w = swb >> 3, h = swb & 7;
  int rr = w & 511;
  int pat = (((rr>>6)==7)?4:0) | ((((rr>>3)&7)==7)?2:0) | (((rr&7)==7)?1:0);
  const unsigned short* cb = combo + ((size_t)pat*8 + h)*9604;
  const unsigned short* qb = qkv + ((size_t)w*8 + h)*3136;
  const unsigned short* kb = qb + 25690112;
  const unsigned short* vb = kb + 25690112;

  unsigned short* Pw = &P[wid][0];
  { int rp = lane >> 2, cc = 112 + (lane & 3)*4;
    *(uint2*)&Pw[rp*136 + cc] = make_uint2(0u, 0u); }   // zero pad cols 112..127 (never rewritten)

  for (int pass = 0; pass < 2; pass++){
    int mt = wid + pass*4;
    if (mt > 6) break;

    int qrow = mt*16 + l16; if (qrow > 97) qrow = 97;
    bf16x8 qa = *(const bf16x8*)(qb + qrow*32 + lk*8);

    f32x4 s[7];
    #pragma unroll
    for (int nt = 0; nt < 7; nt++){
      int kc = nt*16 + l16; if (kc > 97) kc = 97;
      bf16x8 kf = *(const bf16x8*)(kb + kc*32 + lk*8);
      f32x4 z = (f32x4){0.f,0.f,0.f,0.f};
      s[nt] = __builtin_amdgcn_mfma_f32_16x16x32_bf16(qa, kf, z, 0, 0, 0);
    }

    float mx[4] = {-3e38f,-3e38f,-3e38f,-3e38f};
    #pragma unroll
    for (int r = 0; r < 4; r++){
      int gi = mt*16 + lk*4 + r; if (gi > 97) gi = 97;
      int ibase = gi*98;
      #pragma unroll
      for (int nt = 0; nt < 7; nt++){
        int j = nt*16 + l16;
        float add = (j < 98) ? bf2f(cb[ibase + j]) : -1e30f;
        float val = s[nt][r] + add;
        s[nt][r] = val;
        mx[r] = fmaxf(mx[r], val);
      }
    }
    #pragma unroll
    for (int r = 0; r < 4; r++){
      #pragma unroll
      for (int off = 1; off < 16; off <<= 1) mx[r] = fmaxf(mx[r], __shfl_xor(mx[r], off));
    }
    float sm[4] = {0.f,0.f,0.f,0.f};
    #pragma unroll
    for (int r = 0; r < 4; r++){
      #pragma unroll
      for (int nt = 0; nt < 7; nt++){
        float e = __expf(s[nt][r] - mx[r]);
        s[nt][r] = e; sm[r] += e;
      }
    }
    #pragma unroll
    for (int r = 0; r < 4; r++){
      #pragma unroll
      for (int off = 1; off < 16; off <<= 1) sm[r] += __shfl_xor(sm[r], off);
      sm[r] = 1.f / sm[r];
    }

    #pragma unroll
    for (int r = 0; r < 4; r++)
      #pragma unroll
      for (int nt = 0; nt < 7; nt++)
        Pw[(lk*4 + r)*136 + nt*16 + l16] = f2bf(s[nt][r]*sm[r]);

    f32x4 o0 = (f32x4){0.f,0.f,0.f,0.f}, o1 = (f32x4){0.f,0.f,0.f,0.f};
    #pragma unroll
    for (int kcc = 0; kcc < 4; kcc++){
      bf16x8 pa = *(const bf16x8*)&Pw[l16*136 + kcc*32 + lk*8];
      bf16x8 v0, v1;
      #pragma unroll
      for (int j = 0; j < 8; j++){
        int k = kcc*32 + lk*8 + j; if (k > 97) k = 97;   // P is zero there anyway
        v0[j] = (short)vb[k*32 + l16];
        v1[j] = (short)vb[k*32 + 16 + l16];
      }
      o0 = __builtin_amdgcn_mfma_f32_16x16x32_bf16(pa, v0, o0, 0, 0, 0);
      o1 = __builtin_amdgcn_mfma_f32_16x16x32_bf16(pa, v1, o1, 0, 0, 0);
    }
    #pragma unroll
    for (int r = 0; r < 4; r++){
      int n = mt*16 + lk*4 + r;
      if (n < 98){
        size_t ob = ((size_t)w*98 + n)*256 + h*32;
        obuf[ob + l16]      = f2bf(o0[r]);
        obuf[ob + 16 + l16] = f2bf(o1[r]);
      }
    }
  }
}

extern "C" void kernel_launch(void* const* d_in, const int* in_sizes, int n_in,
                              void* d_out, int out_size, void* d_ws, size_t ws_size,
                              hipStream_t stream)
{
  const float* x     = (const float*)d_in[0];
  const float* maskm = (const float*)d_in[1];
  const int*   ri    = (const int*)d_in[2];
  const float* tbl   = (const float*)d_in[3];
  const float* n1w   = (const float*)d_in[4];
  const float* n1b   = (const float*)d_in[5];
  const float* qkvw  = (const float*)d_in[6];
  const float* qkvbv = (const float*)d_in[7];
  const float* projw = (const float*)d_in[8];
  const float* projb = (const float*)d_in[9];
  const float* n2w   = (const float*)d_in[10];
  const float* n2b   = (const float*)d_in[11];
  const float* fc1w  = (const float*)d_in[12];
  const float* fc1b  = (const float*)d_in[13];
  const float* fc2w  = (const float*)d_in[14];
  const float* fc2b  = (const float*)d_in[15];
  float* dout = (float*)d_out;
  char* ws = (char*)d_ws;

  // ---- part-1 workspace layout (peak 207.27 MB, under proven 207.62) ----
  unsigned short* qkvB = (unsigned short*)(ws + 0);           // 3*25690112 bf16 = 154,140,672 B
  unsigned short* hb   = (unsigned short*)(ws + 154140672);   // 100352*256 bf16 = 51,380,224 B (LN1 out, then attn out)
  unsigned short* wq   = (unsigned short*)(ws + 205520896);   // 768*256 bf16
  unsigned short* wp   = (unsigned short*)(ws + 205914112);   // 256*256 bf16
  unsigned short* combo= (unsigned short*)(ws + 206045184);   // 8*8*9604 bf16 = 1,229,312 B -> end 207,274,496
  // ---- part-2 layout (inside dead qkvB region) ----
  unsigned short* h2 = (unsigned short*)(ws + 0);             // 100352*256 bf16
  unsigned short* g  = (unsigned short*)(ws + 51380224);      // 25088*1024 bf16
  unsigned short* w1 = (unsigned short*)(ws + 102760448);     // 1024*256 bf16
  unsigned short* w2 = (unsigned short*)(ws + 103284736);     // 256*1024 bf16

  cvtk<<<768, 256, 0, stream>>>(qkvw, wq, 196608);
  cvtk<<<256, 256, 0, stream>>>(projw, wp, 65536);
  combok<<<2402, 256, 0, stream>>>(ri, tbl, maskm, combo);

  lnk<<<25088, 256, 0, stream>>>(x, n1w, n1b, hb, 0);                                      // LN1+shift+window
  gemmk<0><<<784*6, 256, 0, stream>>>(hb, wq, qkvbv, 256, 6, qkvB, nullptr, nullptr, 0);   // qkv
  attnk<<<8192, 256, 0, stream>>>(qkvB, combo, hb);                                        // attention
  gemmk<1><<<784*2, 256, 0, stream>>>(hb, wp, projb, 256, 2, nullptr, x, dout, 0);         // proj+residual

  cvtk<<<1024, 256, 0, stream>>>(fc1w, w1, 262144);   // into dead qkv space
  cvtk<<<1024, 256, 0, stream>>>(fc2w, w2, 262144);
  lnk<<<25088, 256, 0, stream>>>(dout, n2w, n2b, h2, 1);                                   // LN2
  for (int c = 0; c < 4; c++){
    gemmk<2><<<196*8, 256, 0, stream>>>(h2 + (size_t)c*25088*256, w1, fc1b, 256, 8, g, nullptr, nullptr, 0);
    gemmk<3><<<196*2, 256, 0, stream>>>(g, w2, fc2b, 1024, 2, nullptr, nullptr, dout, c*25088);
  }
}

// Round 4
// 528.719 us; speedup vs baseline: 1.4424x; 1.0866x over previous
//
#include <hip/hip_runtime.h>
#include <hip/hip_bf16.h>

typedef __attribute__((ext_vector_type(8))) short bf16x8;
typedef __attribute__((ext_vector_type(4))) float f32x4;

__device__ __forceinline__ unsigned short f2bf(float f){
  __hip_bfloat16 h = __float2bfloat16(f);
  return *reinterpret_cast<unsigned short*>(&h);
}
__device__ __forceinline__ float bf2f(unsigned short u){
  unsigned int v = ((unsigned int)u) << 16;
  return __uint_as_float(v);
}

#define GLDS16(gptr, lptr) \
  __builtin_amdgcn_global_load_lds((const __attribute__((address_space(1))) unsigned int*)(gptr), \
                                   (__attribute__((address_space(3))) unsigned int*)(lptr), 16, 0, 0)

// ---------------- small prep kernels ----------------
__global__ void cvtk(const float* __restrict__ s, unsigned short* __restrict__ d, int n){
  int i = blockIdx.x*256 + threadIdx.x;
  if (i < n) d[i] = f2bf(s[i]);
}

// comboX[pat][h][mt][nt][lane][r] = rel_bias + mask_pattern, bf16, pre-permuted to the
// exact 16x16x32 MFMA D fragment layout (col = lane&15, row = (lane>>4)*4 + r).
// idx = ((((pat*8+h)*7 + mt)*7 + nt)*64 + lane)*4 + r ; total 802816 elems (1.6 MB).
__global__ void combok(const int* __restrict__ ri, const float* __restrict__ tbl,
                       const float* __restrict__ mask, unsigned short* __restrict__ out){
  int g = blockIdx.x*256 + threadIdx.x;
  if (g >= 802816) return;
  int r = g & 3;
  int t = g >> 2;
  int lane = t & 63; t >>= 6;
  int nt = t % 7; t /= 7;
  int mt = t % 7; t /= 7;
  int p = t >> 3, h = t & 7;
  int gi = mt*16 + (lane >> 4)*4 + r; if (gi > 97) gi = 97;
  int j  = nt*16 + (lane & 15);
  float v;
  if (j < 98){
    int wrep = ((p&4)?448:0) + ((p&2)?56:0) + ((p&1)?7:0);
    v = tbl[ri[gi*98 + j]*8 + h] + mask[(size_t)wrep*9604 + gi*98 + j];
  } else {
    v = -30000.f;
  }
  out[g] = f2bf(v);
}

// ---------------- LayerNorm (+optional shift/window map) ----------------
__launch_bounds__(256)
__global__ void lnk(const float* __restrict__ xin, const float* __restrict__ gw, const float* __restrict__ gb,
                    unsigned short* __restrict__ hout, int mode)
{
  int wid = threadIdx.x >> 6, lane = threadIdx.x & 63;
  int tok = blockIdx.x*4 + wid;
  int src;
  if (mode == 0){
    int w = tok / 98, n = tok % 98;
    int b = w >> 9, rr = w & 511;
    int di = rr >> 6, hi = (rr >> 3) & 7, wi = rr & 7;
    int d2 = n / 49, n2 = n % 49, h2 = n2 / 7, w2 = n2 % 7;
    int sd = (di*2 + d2 + 1) & 15;
    int sh = hi*7 + h2 + 3; if (sh >= 56) sh -= 56;
    int sw = wi*7 + w2 + 3; if (sw >= 56) sw -= 56;
    src = ((b*16 + sd)*56 + sh)*56 + sw;
  } else {
    src = tok;
  }
  float4 v = *(const float4*)(xin + (size_t)src*256 + lane*4);
  float s  = v.x + v.y + v.z + v.w;
  float s2 = v.x*v.x + v.y*v.y + v.z*v.z + v.w*v.w;
  #pragma unroll
  for (int off = 1; off < 64; off <<= 1){
    s  += __shfl_xor(s, off);
    s2 += __shfl_xor(s2, off);
  }
  float mean = s * (1.f/256.f);
  float var  = s2 * (1.f/256.f) - mean*mean;
  float rstd = rsqrtf(var + 1e-5f);
  int c = lane*4;
  float4 wv = *(const float4*)(gw + c);
  float4 bv = *(const float4*)(gb + c);
  unsigned int p0 = (unsigned int)f2bf((v.x-mean)*rstd*wv.x + bv.x)
                  | ((unsigned int)f2bf((v.y-mean)*rstd*wv.y + bv.y) << 16);
  unsigned int p1 = (unsigned int)f2bf((v.z-mean)*rstd*wv.z + bv.z)
                  | ((unsigned int)f2bf((v.w-mean)*rstd*wv.w + bv.w) << 16);
  uint2 pk; pk.x = p0; pk.y = p1;
  *(uint2*)(hout + (size_t)tok*256 + c) = pk;
}

// ---------------- bf16 MFMA GEMM: C[M,N] = A[M,K] * Bw[N,K]^T + bias ----------------
// XCD-chunked bijective block swizzle (grid always divisible by 8).
// EPI 0: qkv scatter per-head (+q scale)   EPI 1: proj + unwindow/unroll + residual
// EPI 2: fc1 + GELU(erf) -> bf16           EPI 3: fc2 accumulate into d_out
template<int EPI>
__launch_bounds__(256, 2)
__global__ void gemmk(const unsigned short* __restrict__ A, const unsigned short* __restrict__ Bw,
                      const float* __restrict__ bias, int K, int nbx,
                      unsigned short* __restrict__ outb, const float* __restrict__ xres,
                      float* __restrict__ outf, int moff)
{
  __shared__ unsigned short As[128*32];
  __shared__ unsigned short Bs[128*32];
  int tid = threadIdx.x;
  int wid = tid >> 6, lane = tid & 63, l16 = lane & 15, lk = lane >> 4;
  int wm = wid >> 1, wn = wid & 1;
  int cpx = gridDim.x >> 3;
  int swb = (blockIdx.x & 7)*cpx + (blockIdx.x >> 3);
  int mblk = swb / nbx, nblk = swb % nbx;
  const unsigned short* Ab = A  + (size_t)mblk*128*K;
  const unsigned short* Bb = Bw + (size_t)nblk*128*K;
  int rA = tid >> 2, kcA = (tid & 3)*8;

  f32x4 acc[4][4];
  #pragma unroll
  for (int i = 0; i < 4; i++)
    #pragma unroll
    for (int j = 0; j < 4; j++)
      acc[i][j] = (f32x4){0.f,0.f,0.f,0.f};

  for (int ks = 0; ks < K; ks += 32){
    __syncthreads();
    GLDS16(Ab + (size_t)rA*K      + ks + kcA, &As[wid*512]);
    GLDS16(Ab + (size_t)(rA+64)*K + ks + kcA, &As[2048 + wid*512]);
    GLDS16(Bb + (size_t)rA*K      + ks + kcA, &Bs[wid*512]);
    GLDS16(Bb + (size_t)(rA+64)*K + ks + kcA, &Bs[2048 + wid*512]);
    __syncthreads();
    bf16x8 af[4], bfr[4];
    #pragma unroll
    for (int mi = 0; mi < 4; mi++) af[mi]  = *(const bf16x8*)&As[(wm*64 + mi*16 + l16)*32 + lk*8];
    #pragma unroll
    for (int ni = 0; ni < 4; ni++) bfr[ni] = *(const bf16x8*)&Bs[(wn*64 + ni*16 + l16)*32 + lk*8];
    #pragma unroll
    for (int mi = 0; mi < 4; mi++)
      #pragma unroll
      for (int ni = 0; ni < 4; ni++)
        acc[mi][ni] = __builtin_amdgcn_mfma_f32_16x16x32_bf16(af[mi], bfr[ni], acc[mi][ni], 0, 0, 0);
  }

  int rowb = mblk*128 + wm*64;
  int colb = nblk*128 + wn*64;
  #pragma unroll
  for (int mi = 0; mi < 4; mi++){
    #pragma unroll
    for (int r = 0; r < 4; r++){
      int row = rowb + mi*16 + lk*4 + r;
      if constexpr (EPI == 0){
        int w = row / 98, n = row % 98;
        size_t obase = ((size_t)w*8)*3136 + (size_t)n*32;
        #pragma unroll
        for (int ni = 0; ni < 4; ni++){
          int col = colb + ni*16 + l16;
          float v = acc[mi][ni][r] + bias[col];
          int which = col >> 8, head = (col >> 5) & 7, e = col & 31;
          if (which == 0) v *= 0.17677669529663687f;
          outb[(size_t)which*25690112 + obase + (size_t)head*3136 + e] = f2bf(v);
        }
      } else if constexpr (EPI == 1){
        int w = row / 98, n = row % 98;
        int b = w >> 9, rr = w & 511;
        int di = rr >> 6, hi = (rr >> 3) & 7, wi = rr & 7;
        int d2 = n / 49, n2 = n % 49, h2 = n2 / 7, w2 = n2 % 7;
        int sd = (di*2 + d2 + 1) & 15;
        int sh = hi*7 + h2 + 3; if (sh >= 56) sh -= 56;
        int sw = wi*7 + w2 + 3; if (sw >= 56) sw -= 56;
        size_t tnat = (((size_t)b*16 + sd)*56 + sh)*56 + sw;
        #pragma unroll
        for (int ni = 0; ni < 4; ni++){
          int col = colb + ni*16 + l16;
          float v = acc[mi][ni][r] + bias[col];
          outf[tnat*256 + col] = xres[tnat*256 + col] + v;
        }
      } else if constexpr (EPI == 2){
        #pragma unroll
        for (int ni = 0; ni < 4; ni++){
          int col = colb + ni*16 + l16;
          float v = acc[mi][ni][r] + bias[col];
          float gl = v * 0.5f * (1.f + erff(v * 0.70710678118654752f));
          outb[(size_t)row*1024 + col] = f2bf(gl);
        }
      } else {
        #pragma unroll
        for (int ni = 0; ni < 4; ni++){
          int col = colb + ni*16 + l16;
          float v = acc[mi][ni][r] + bias[col];
          outf[((size_t)(moff + row))*256 + col] += v;
        }
      }
    }
  }
}

// ---------------- fused window attention ----------------
// One WAVE owns one (window, head) and iterates all 7 m-tiles.
// V fragments gathered to registers ONCE per wave (amortized over 7 tiles);
// K reloaded per tile (coalesced dwordx4, L1-hot); combo adds via pre-permuted
// comboX (7 coalesced uint2 loads per tile). Per-wave P region in LDS, no barriers.
__launch_bounds__(256)
__global__ void attnk(const unsigned short* __restrict__ qkv, const unsigned short* __restrict__ comboX,
                      unsigned short* __restrict__ obuf)
{
  __shared__ unsigned short P[4][16*136];   // stride 136 breaks the 256B-stride bank conflict
  int tid = threadIdx.x, wid = tid >> 6, lane = tid & 63, l16 = lane & 15, lk = lane >> 4;
  int cpx = gridDim.x >> 3;
  int swb = (blockIdx.x & 7)*cpx + (blockIdx.x >> 3);
  int task = swb*4 + wid;                   // 2048 blocks * 4 waves = 8192 (w,h) tasks
  int w = task >> 3, h = task & 7;
  int rr = w & 511;
  int pat = (((rr>>6)==7)?4:0) | ((((rr>>3)&7)==7)?2:0) | (((rr&7)==7)?1:0);
  const unsigned short* cb = comboX + (size_t)(pat*8 + h)*12544;   // 7mt*7nt*256
  const unsigned short* qb = qkv + ((size_t)w*8 + h)*3136;
  const unsigned short* kb = qb + 25690112;
  const unsigned short* vb = kb + 25690112;

  // V fragments (transposed gather) once per wave
  bf16x8 v0[4], v1[4];
  #pragma unroll
  for (int kcc = 0; kcc < 4; kcc++){
    #pragma unroll
    for (int j = 0; j < 8; j++){
      int k = kcc*32 + lk*8 + j; if (k > 97) k = 97;   // P is zero past col 97
      v0[kcc][j] = (short)vb[k*32 + l16];
      v1[kcc][j] = (short)vb[k*32 + 16 + l16];
    }
  }

  unsigned short* Pw = &P[wid][0];
  { int rp = lane >> 2, cc = 112 + (lane & 3)*4;
    *(uint2*)&Pw[rp*136 + cc] = make_uint2(0u, 0u); }   // zero pad cols 112..127 (never rewritten)

  for (int mt = 0; mt < 7; mt++){
    int qrow = mt*16 + l16; if (qrow > 97) qrow = 97;
    bf16x8 qa = *(const bf16x8*)(qb + qrow*32 + lk*8);

    f32x4 s[7];
    #pragma unroll
    for (int nt = 0; nt < 7; nt++){
      int kc = nt*16 + l16; if (kc > 97) kc = 97;
      bf16x8 kf = *(const bf16x8*)(kb + kc*32 + lk*8);
      f32x4 z = (f32x4){0.f,0.f,0.f,0.f};
      s[nt] = __builtin_amdgcn_mfma_f32_16x16x32_bf16(qa, kf, z, 0, 0, 0);
    }

    const unsigned short* cm = cb + mt*1792;
    float mx[4] = {-3e38f,-3e38f,-3e38f,-3e38f};
    #pragma unroll
    for (int nt = 0; nt < 7; nt++){
      uint2 c2 = *(const uint2*)(cm + (nt*64 + lane)*4);
      s[nt][0] += bf2f((unsigned short)(c2.x & 0xffff));
      s[nt][1] += bf2f((unsigned short)(c2.x >> 16));
      s[nt][2] += bf2f((unsigned short)(c2.y & 0xffff));
      s[nt][3] += bf2f((unsigned short)(c2.y >> 16));
      mx[0] = fmaxf(mx[0], s[nt][0]); mx[1] = fmaxf(mx[1], s[nt][1]);
      mx[2] = fmaxf(mx[2], s[nt][2]); mx[3] = fmaxf(mx[3], s[nt][3]);
    }
    #pragma unroll
    for (int r = 0; r < 4; r++){
      #pragma unroll
      for (int off = 1; off < 16; off <<= 1) mx[r] = fmaxf(mx[r], __shfl_xor(mx[r], off));
    }
    float sm[4] = {0.f,0.f,0.f,0.f};
    #pragma unroll
    for (int r = 0; r < 4; r++){
      #pragma unroll
      for (int nt = 0; nt < 7; nt++){
        float e = __expf(s[nt][r] - mx[r]);
        s[nt][r] = e; sm[r] += e;
      }
    }
    #pragma unroll
    for (int r = 0; r < 4; r++){
      #pragma unroll
      for (int off = 1; off < 16; off <<= 1) sm[r] += __shfl_xor(sm[r], off);
      sm[r] = 1.f / sm[r];
    }

    #pragma unroll
    for (int r = 0; r < 4; r++)
      #pragma unroll
      for (int nt = 0; nt < 7; nt++)
        Pw[(lk*4 + r)*136 + nt*16 + l16] = f2bf(s[nt][r]*sm[r]);

    f32x4 o0 = (f32x4){0.f,0.f,0.f,0.f}, o1 = (f32x4){0.f,0.f,0.f,0.f};
    #pragma unroll
    for (int kcc = 0; kcc < 4; kcc++){
      bf16x8 pa = *(const bf16x8*)&Pw[l16*136 + kcc*32 + lk*8];
      o0 = __builtin_amdgcn_mfma_f32_16x16x32_bf16(pa, v0[kcc], o0, 0, 0, 0);
      o1 = __builtin_amdgcn_mfma_f32_16x16x32_bf16(pa, v1[kcc], o1, 0, 0, 0);
    }
    #pragma unroll
    for (int r = 0; r < 4; r++){
      int n = mt*16 + lk*4 + r;
      if (n < 98){
        size_t ob = ((size_t)w*98 + n)*256 + h*32;
        obuf[ob + l16]      = f2bf(o0[r]);
        obuf[ob + 16 + l16] = f2bf(o1[r]);
      }
    }
  }
}

extern "C" void kernel_launch(void* const* d_in, const int* in_sizes, int n_in,
                              void* d_out, int out_size, void* d_ws, size_t ws_size,
                              hipStream_t stream)
{
  const float* x     = (const float*)d_in[0];
  const float* maskm = (const float*)d_in[1];
  const int*   ri    = (const int*)d_in[2];
  const float* tbl   = (const float*)d_in[3];
  const float* n1w   = (const float*)d_in[4];
  const float* n1b   = (const float*)d_in[5];
  const float* qkvw  = (const float*)d_in[6];
  const float* qkvbv = (const float*)d_in[7];
  const float* projw = (const float*)d_in[8];
  const float* projb = (const float*)d_in[9];
  const float* n2w   = (const float*)d_in[10];
  const float* n2b   = (const float*)d_in[11];
  const float* fc1w  = (const float*)d_in[12];
  const float* fc1b  = (const float*)d_in[13];
  const float* fc2w  = (const float*)d_in[14];
  const float* fc2b  = (const float*)d_in[15];
  float* dout = (float*)d_out;
  char* ws = (char*)d_ws;

  // ---- part-1 layout (peak 207.52 MB, under proven 207.62) ----
  unsigned short* qkvB  = (unsigned short*)(ws + 0);           // 3*25690112 bf16 = 154,140,672 B
  unsigned short* hb    = (unsigned short*)(ws + 154140672);   // 100352*256 bf16 (LN1 out, then attn out)
  unsigned short* wq    = (unsigned short*)(ws + 205520896);   // 768*256 bf16
  unsigned short* comboX= (unsigned short*)(ws + 205914112);   // 802816 bf16 = 1,605,632 B -> end 207,519,744
  unsigned short* wp    = (unsigned short*)(ws + 0);           // 256*256 bf16, created AFTER attnk (qkv q-region dead)
  // ---- part-2 layout (inside dead qkvB region) ----
  unsigned short* h2 = (unsigned short*)(ws + 0);              // 100352*256 bf16
  unsigned short* g  = (unsigned short*)(ws + 51380224);       // 25088*1024 bf16
  unsigned short* w1 = (unsigned short*)(ws + 102760448);      // 1024*256 bf16
  unsigned short* w2 = (unsigned short*)(ws + 103284736);      // 256*1024 bf16

  cvtk<<<768, 256, 0, stream>>>(qkvw, wq, 196608);
  combok<<<3136, 256, 0, stream>>>(ri, tbl, maskm, comboX);

  lnk<<<25088, 256, 0, stream>>>(x, n1w, n1b, hb, 0);                                      // LN1+shift+window
  gemmk<0><<<784*6, 256, 0, stream>>>(hb, wq, qkvbv, 256, 6, qkvB, nullptr, nullptr, 0);   // qkv
  attnk<<<2048, 256, 0, stream>>>(qkvB, comboX, hb);                                       // attention
  cvtk<<<256, 256, 0, stream>>>(projw, wp, 65536);                                         // into dead q space
  gemmk<1><<<784*2, 256, 0, stream>>>(hb, wp, projb, 256, 2, nullptr, x, dout, 0);         // proj+residual

  cvtk<<<1024, 256, 0, stream>>>(fc1w, w1, 262144);   // into dead qkv space
  cvtk<<<1024, 256, 0, stream>>>(fc2w, w2, 262144);
  lnk<<<25088, 256, 0, stream>>>(dout, n2w, n2b, h2, 1);                                   // LN2
  for (int c = 0; c < 4; c++){
    gemmk<2><<<196*8, 256, 0, stream>>>(h2 + (size_t)c*25088*256, w1, fc1b, 256, 8, g, nullptr, nullptr, 0);
    gemmk<3><<<196*2, 256, 0, stream>>>(g, w2, fc2b, 1024, 2, nullptr, nullptr, dout, c*25088);
  }
}

// Round 5
// 513.265 us; speedup vs baseline: 1.4859x; 1.0301x over previous
//
#include <hip/hip_runtime.h>
#include <hip/hip_bf16.h>

typedef __attribute__((ext_vector_type(8))) short bf16x8;
typedef __attribute__((ext_vector_type(4))) float f32x4;

__device__ __forceinline__ unsigned short f2bf(float f){
  __hip_bfloat16 h = __float2bfloat16(f);
  return *reinterpret_cast<unsigned short*>(&h);
}

#define GLDS16(gptr, lptr) \
  __builtin_amdgcn_global_load_lds((const __attribute__((address_space(1))) unsigned int*)(gptr), \
                                   (__attribute__((address_space(3))) unsigned int*)(lptr), 16, 0, 0)

// ---------------- small prep kernels ----------------
__global__ void cvtk(const float* __restrict__ s, unsigned short* __restrict__ d, int n){
  int i = blockIdx.x*256 + threadIdx.x;
  if (i < n) d[i] = f2bf(s[i]);
}

// comboX[pat][h][mt][nt][lane][r] = rel_bias + mask_pattern, bf16, pre-permuted to the
// exact 16x16x32 MFMA D fragment layout (col = lane&15, row = (lane>>4)*4 + r).
__global__ void combok(const int* __restrict__ ri, const float* __restrict__ tbl,
                       const float* __restrict__ mask, unsigned short* __restrict__ out){
  int g = blockIdx.x*256 + threadIdx.x;
  if (g >= 802816) return;
  int r = g & 3;
  int t = g >> 2;
  int lane = t & 63; t >>= 6;
  int nt = t % 7; t /= 7;
  int mt = t % 7; t /= 7;
  int p = t >> 3, h = t & 7;
  int gi = mt*16 + (lane >> 4)*4 + r; if (gi > 97) gi = 97;
  int j  = nt*16 + (lane & 15);
  float v;
  if (j < 98){
    int wrep = ((p&4)?448:0) + ((p&2)?56:0) + ((p&1)?7:0);
    v = tbl[ri[gi*98 + j]*8 + h] + mask[(size_t)wrep*9604 + gi*98 + j];
  } else {
    v = -30000.f;
  }
  out[g] = f2bf(v);
}

// ---------------- LayerNorm (+optional shift/window map) ----------------
__launch_bounds__(256)
__global__ void lnk(const float* __restrict__ xin, const float* __restrict__ gw, const float* __restrict__ gb,
                    unsigned short* __restrict__ hout, int mode)
{
  int wid = threadIdx.x >> 6, lane = threadIdx.x & 63;
  int tok = blockIdx.x*4 + wid;
  int src;
  if (mode == 0){
    int w = tok / 98, n = tok % 98;
    int b = w >> 9, rr = w & 511;
    int di = rr >> 6, hi = (rr >> 3) & 7, wi = rr & 7;
    int d2 = n / 49, n2 = n % 49, h2 = n2 / 7, w2 = n2 % 7;
    int sd = (di*2 + d2 + 1) & 15;
    int sh = hi*7 + h2 + 3; if (sh >= 56) sh -= 56;
    int sw = wi*7 + w2 + 3; if (sw >= 56) sw -= 56;
    src = ((b*16 + sd)*56 + sh)*56 + sw;
  } else {
    src = tok;
  }
  float4 v = *(const float4*)(xin + (size_t)src*256 + lane*4);
  float s  = v.x + v.y + v.z + v.w;
  float s2 = v.x*v.x + v.y*v.y + v.z*v.z + v.w*v.w;
  #pragma unroll
  for (int off = 1; off < 64; off <<= 1){
    s  += __shfl_xor(s, off);
    s2 += __shfl_xor(s2, off);
  }
  float mean = s * (1.f/256.f);
  float var  = s2 * (1.f/256.f) - mean*mean;
  float rstd = rsqrtf(var + 1e-5f);
  int c = lane*4;
  float4 wv = *(const float4*)(gw + c);
  float4 bv = *(const float4*)(gb + c);
  unsigned int p0 = (unsigned int)f2bf((v.x-mean)*rstd*wv.x + bv.x)
                  | ((unsigned int)f2bf((v.y-mean)*rstd*wv.y + bv.y) << 16);
  unsigned int p1 = (unsigned int)f2bf((v.z-mean)*rstd*wv.z + bv.z)
                  | ((unsigned int)f2bf((v.w-mean)*rstd*wv.w + bv.w) << 16);
  uint2 pk; pk.x = p0; pk.y = p1;
  *(uint2*)(hout + (size_t)tok*256 + c) = pk;
}

// ---------------- bf16 MFMA GEMM: C[M,N] = A[M,K] * Bw[N,K]^T + bias ----------------
// XCD-chunked bijective block swizzle (grid always divisible by 8).
// EPI 0: qkv plain [row][768] (+q scale on cols<256)
// EPI 1: proj + unwindow/unroll + residual
// EPI 2: fc1 + GELU(erf) -> bf16           EPI 3: fc2 accumulate into d_out
template<int EPI>
__launch_bounds__(256, 2)
__global__ void gemmk(const unsigned short* __restrict__ A, const unsigned short* __restrict__ Bw,
                      const float* __restrict__ bias, int K, int nbx,
                      unsigned short* __restrict__ outb, const float* __restrict__ xres,
                      float* __restrict__ outf, int moff)
{
  __shared__ unsigned short As[128*32];
  __shared__ unsigned short Bs[128*32];
  int tid = threadIdx.x;
  int wid = tid >> 6, lane = tid & 63, l16 = lane & 15, lk = lane >> 4;
  int wm = wid >> 1, wn = wid & 1;
  int cpx = gridDim.x >> 3;
  int swb = (blockIdx.x & 7)*cpx + (blockIdx.x >> 3);
  int mblk = swb / nbx, nblk = swb % nbx;
  const unsigned short* Ab = A  + (size_t)mblk*128*K;
  const unsigned short* Bb = Bw + (size_t)nblk*128*K;
  int rA = tid >> 2, kcA = (tid & 3)*8;

  f32x4 acc[4][4];
  #pragma unroll
  for (int i = 0; i < 4; i++)
    #pragma unroll
    for (int j = 0; j < 4; j++)
      acc[i][j] = (f32x4){0.f,0.f,0.f,0.f};

  for (int ks = 0; ks < K; ks += 32){
    __syncthreads();
    GLDS16(Ab + (size_t)rA*K      + ks + kcA, &As[wid*512]);
    GLDS16(Ab + (size_t)(rA+64)*K + ks + kcA, &As[2048 + wid*512]);
    GLDS16(Bb + (size_t)rA*K      + ks + kcA, &Bs[wid*512]);
    GLDS16(Bb + (size_t)(rA+64)*K + ks + kcA, &Bs[2048 + wid*512]);
    __syncthreads();
    bf16x8 af[4], bfr[4];
    #pragma unroll
    for (int mi = 0; mi < 4; mi++) af[mi]  = *(const bf16x8*)&As[(wm*64 + mi*16 + l16)*32 + lk*8];
    #pragma unroll
    for (int ni = 0; ni < 4; ni++) bfr[ni] = *(const bf16x8*)&Bs[(wn*64 + ni*16 + l16)*32 + lk*8];
    #pragma unroll
    for (int mi = 0; mi < 4; mi++)
      #pragma unroll
      for (int ni = 0; ni < 4; ni++)
        acc[mi][ni] = __builtin_amdgcn_mfma_f32_16x16x32_bf16(af[mi], bfr[ni], acc[mi][ni], 0, 0, 0);
  }

  int rowb = mblk*128 + wm*64;
  int colb = nblk*128 + wn*64;
  #pragma unroll
  for (int mi = 0; mi < 4; mi++){
    #pragma unroll
    for (int r = 0; r < 4; r++){
      int row = rowb + mi*16 + lk*4 + r;
      if constexpr (EPI == 0){
        #pragma unroll
        for (int ni = 0; ni < 4; ni++){
          int col = colb + ni*16 + l16;
          float v = acc[mi][ni][r] + bias[col];
          if (col < 256) v *= 0.17677669529663687f;
          outb[(size_t)row*768 + col] = f2bf(v);
        }
      } else if constexpr (EPI == 1){
        int w = row / 98, n = row % 98;
        int b = w >> 9, rr = w & 511;
        int di = rr >> 6, hi = (rr >> 3) & 7, wi = rr & 7;
        int d2 = n / 49, n2 = n % 49, h2 = n2 / 7, w2 = n2 % 7;
        int sd = (di*2 + d2 + 1) & 15;
        int sh = hi*7 + h2 + 3; if (sh >= 56) sh -= 56;
        int sw = wi*7 + w2 + 3; if (sw >= 56) sw -= 56;
        size_t tnat = (((size_t)b*16 + sd)*56 + sh)*56 + sw;
        #pragma unroll
        for (int ni = 0; ni < 4; ni++){
          int col = colb + ni*16 + l16;
          float v = acc[mi][ni][r] + bias[col];
          outf[tnat*256 + col] = xres[tnat*256 + col] + v;
        }
      } else if constexpr (EPI == 2){
        #pragma unroll
        for (int ni = 0; ni < 4; ni++){
          int col = colb + ni*16 + l16;
          float v = acc[mi][ni][r] + bias[col];
          float gl = v * 0.5f * (1.f + erff(v * 0.70710678118654752f));
          outb[(size_t)row*1024 + col] = f2bf(gl);
        }
      } else {
        #pragma unroll
        for (int ni = 0; ni < 4; ni++){
          int col = colb + ni*16 + l16;
          float v = acc[mi][ni][r] + bias[col];
          outf[((size_t)(moff + row))*256 + col] += v;
        }
      }
    }
  }
}

// ---------------- fused window attention ----------------
// One WAVE owns one (window, head), iterates all 7 m-tiles.
// qkv in plain [row][768] (q: cols h*32.., k: +256, v: +512).
// V gathered once per wave as e-pairs (u32 loads); combo enters as MFMA C-init
// (bit-unpack only, no adds); packed u32 output stores.
__launch_bounds__(256)
__global__ void attnk(const unsigned short* __restrict__ qkv, const unsigned short* __restrict__ comboX,
                      unsigned short* __restrict__ obuf)
{
  __shared__ unsigned short P[4][16*136];   // stride 136 breaks the 256B-stride bank conflict
  int tid = threadIdx.x, wid = tid >> 6, lane = tid & 63, l16 = lane & 15, lk = lane >> 4;
  int cpx = gridDim.x >> 3;
  int swb = (blockIdx.x & 7)*cpx + (blockIdx.x >> 3);
  int task = swb*4 + wid;                   // 2048 blocks * 4 waves = 8192 (w,h) tasks
  int w = task >> 3, h = task & 7;
  int rr = w & 511;
  int pat = (((rr>>6)==7)?4:0) | ((((rr>>3)&7)==7)?2:0) | (((rr&7)==7)?1:0);
  const unsigned short* cb = comboX + (size_t)(pat*8 + h)*12544;   // 7mt*7nt*256
  const unsigned short* base = qkv + (size_t)w*98*768 + h*32;      // q cols; k +256; v +512

  // V fragments (transposed gather, e-pair order) once per wave
  bf16x8 v0[4], v1[4];
  #pragma unroll
  for (int kcc = 0; kcc < 4; kcc++){
    #pragma unroll
    for (int j = 0; j < 8; j++){
      int k = kcc*32 + lk*8 + j; if (k > 97) k = 97;   // P is zero past col 97
      unsigned int u = *(const unsigned int*)(base + (size_t)k*768 + 512 + 2*l16);
      v0[kcc][j] = (short)(u & 0xffff);
      v1[kcc][j] = (short)(u >> 16);
    }
  }

  unsigned short* Pw = &P[wid][0];
  { int rp = lane >> 2, cc = 112 + (lane & 3)*4;
    *(uint2*)&Pw[rp*136 + cc] = make_uint2(0u, 0u); }   // zero pad cols 112..127 (never rewritten)

  for (int mt = 0; mt < 7; mt++){
    int qrow = mt*16 + l16; if (qrow > 97) qrow = 97;
    bf16x8 qa = *(const bf16x8*)(base + (size_t)qrow*768 + lk*8);

    const unsigned short* cm = cb + mt*1792;
    f32x4 s[7];
    #pragma unroll
    for (int nt = 0; nt < 7; nt++){
      int kc = nt*16 + l16; if (kc > 97) kc = 97;
      bf16x8 kf = *(const bf16x8*)(base + (size_t)kc*768 + 256 + lk*8);
      uint2 c2 = *(const uint2*)(cm + (nt*64 + lane)*4);
      f32x4 ci;
      ci[0] = __uint_as_float(c2.x << 16);
      ci[1] = __uint_as_float(c2.x & 0xffff0000u);
      ci[2] = __uint_as_float(c2.y << 16);
      ci[3] = __uint_as_float(c2.y & 0xffff0000u);
      s[nt] = __builtin_amdgcn_mfma_f32_16x16x32_bf16(qa, kf, ci, 0, 0, 0);
    }

    float mx[4] = {-3e38f,-3e38f,-3e38f,-3e38f};
    #pragma unroll
    for (int nt = 0; nt < 7; nt++){
      mx[0] = fmaxf(mx[0], s[nt][0]); mx[1] = fmaxf(mx[1], s[nt][1]);
      mx[2] = fmaxf(mx[2], s[nt][2]); mx[3] = fmaxf(mx[3], s[nt][3]);
    }
    #pragma unroll
    for (int r = 0; r < 4; r++){
      #pragma unroll
      for (int off = 1; off < 16; off <<= 1) mx[r] = fmaxf(mx[r], __shfl_xor(mx[r], off));
    }
    float sm[4] = {0.f,0.f,0.f,0.f};
    #pragma unroll
    for (int r = 0; r < 4; r++){
      #pragma unroll
      for (int nt = 0; nt < 7; nt++){
        float e = __expf(s[nt][r] - mx[r]);
        s[nt][r] = e; sm[r] += e;
      }
    }
    #pragma unroll
    for (int r = 0; r < 4; r++){
      #pragma unroll
      for (int off = 1; off < 16; off <<= 1) sm[r] += __shfl_xor(sm[r], off);
      sm[r] = 1.f / sm[r];
    }

    #pragma unroll
    for (int r = 0; r < 4; r++)
      #pragma unroll
      for (int nt = 0; nt < 7; nt++)
        Pw[(lk*4 + r)*136 + nt*16 + l16] = f2bf(s[nt][r]*sm[r]);

    f32x4 o0 = (f32x4){0.f,0.f,0.f,0.f}, o1 = (f32x4){0.f,0.f,0.f,0.f};
    #pragma unroll
    for (int kcc = 0; kcc < 4; kcc++){
      bf16x8 pa = *(const bf16x8*)&Pw[l16*136 + kcc*32 + lk*8];
      __builtin_amdgcn_s_setprio(1);
      o0 = __builtin_amdgcn_mfma_f32_16x16x32_bf16(pa, v0[kcc], o0, 0, 0, 0);
      o1 = __builtin_amdgcn_mfma_f32_16x16x32_bf16(pa, v1[kcc], o1, 0, 0, 0);
      __builtin_amdgcn_s_setprio(0);
    }
    #pragma unroll
    for (int r = 0; r < 4; r++){
      int n = mt*16 + lk*4 + r;
      if (n < 98){
        unsigned int pk = (unsigned int)f2bf(o0[r]) | ((unsigned int)f2bf(o1[r]) << 16);
        *(unsigned int*)(obuf + ((size_t)w*98 + n)*256 + h*32 + 2*l16) = pk;
      }
    }
  }
}

extern "C" void kernel_launch(void* const* d_in, const int* in_sizes, int n_in,
                              void* d_out, int out_size, void* d_ws, size_t ws_size,
                              hipStream_t stream)
{
  const float* x     = (const float*)d_in[0];
  const float* maskm = (const float*)d_in[1];
  const int*   ri    = (const int*)d_in[2];
  const float* tbl   = (const float*)d_in[3];
  const float* n1w   = (const float*)d_in[4];
  const float* n1b   = (const float*)d_in[5];
  const float* qkvw  = (const float*)d_in[6];
  const float* qkvbv = (const float*)d_in[7];
  const float* projw = (const float*)d_in[8];
  const float* projb = (const float*)d_in[9];
  const float* n2w   = (const float*)d_in[10];
  const float* n2b   = (const float*)d_in[11];
  const float* fc1w  = (const float*)d_in[12];
  const float* fc1b  = (const float*)d_in[13];
  const float* fc2w  = (const float*)d_in[14];
  const float* fc2b  = (const float*)d_in[15];
  float* dout = (float*)d_out;
  char* ws = (char*)d_ws;

  // ---- part-1 layout (peak 207.52 MB, under proven 207.62) ----
  unsigned short* qkvB  = (unsigned short*)(ws + 0);           // 100352*768 bf16 = 154,140,672 B
  unsigned short* hb    = (unsigned short*)(ws + 154140672);   // 100352*256 bf16 (LN1 out, then attn out)
  unsigned short* wq    = (unsigned short*)(ws + 205520896);   // 768*256 bf16
  unsigned short* comboX= (unsigned short*)(ws + 205914112);   // 802816 bf16 = 1,605,632 B
  unsigned short* wp    = (unsigned short*)(ws + 0);           // 256*256 bf16, created AFTER attnk (qkv dead)
  // ---- part-2 layout (inside dead qkvB region) ----
  unsigned short* h2 = (unsigned short*)(ws + 0);              // 100352*256 bf16
  unsigned short* g  = (unsigned short*)(ws + 51380224);       // 25088*1024 bf16
  unsigned short* w1 = (unsigned short*)(ws + 102760448);      // 1024*256 bf16
  unsigned short* w2 = (unsigned short*)(ws + 103284736);      // 256*1024 bf16

  cvtk<<<768, 256, 0, stream>>>(qkvw, wq, 196608);
  combok<<<3136, 256, 0, stream>>>(ri, tbl, maskm, comboX);

  lnk<<<25088, 256, 0, stream>>>(x, n1w, n1b, hb, 0);                                      // LN1+shift+window
  gemmk<0><<<784*6, 256, 0, stream>>>(hb, wq, qkvbv, 256, 6, qkvB, nullptr, nullptr, 0);   // qkv
  attnk<<<2048, 256, 0, stream>>>(qkvB, comboX, hb);                                       // attention
  cvtk<<<256, 256, 0, stream>>>(projw, wp, 65536);                                         // into dead q space
  gemmk<1><<<784*2, 256, 0, stream>>>(hb, wp, projb, 256, 2, nullptr, x, dout, 0);         // proj+residual

  cvtk<<<1024, 256, 0, stream>>>(fc1w, w1, 262144);   // into dead qkv space
  cvtk<<<1024, 256, 0, stream>>>(fc2w, w2, 262144);
  lnk<<<25088, 256, 0, stream>>>(dout, n2w, n2b, h2, 1);                                   // LN2
  for (int c = 0; c < 4; c++){
    gemmk<2><<<196*8, 256, 0, stream>>>(h2 + (size_t)c*25088*256, w1, fc1b, 256, 8, g, nullptr, nullptr, 0);
    gemmk<3><<<196*2, 256, 0, stream>>>(g, w2, fc2b, 1024, 2, nullptr, nullptr, dout, c*25088);
  }
}

// Round 6
// 487.254 us; speedup vs baseline: 1.5652x; 1.0534x over previous
//
#include <hip/hip_runtime.h>
#include <hip/hip_bf16.h>

typedef __attribute__((ext_vector_type(8))) short bf16x8;
typedef __attribute__((ext_vector_type(4))) float f32x4;

__device__ __forceinline__ unsigned short f2bf(float f){
  __hip_bfloat16 h = __float2bfloat16(f);
  return *reinterpret_cast<unsigned short*>(&h);
}

#define GLDS16(gptr, lptr) \
  __builtin_amdgcn_global_load_lds((const __attribute__((address_space(1))) unsigned int*)(gptr), \
                                   (__attribute__((address_space(3))) unsigned int*)(lptr), 16, 0, 0)

// ---------------- small prep kernels ----------------
__global__ void cvtk(const float* __restrict__ s, unsigned short* __restrict__ d, int n){
  int i = blockIdx.x*256 + threadIdx.x;
  if (i < n) d[i] = f2bf(s[i]);
}

// comboX[pat][h][mt][nt][lane][r] = rel_bias + mask_pattern, bf16, pre-permuted to the
// exact 16x16x32 MFMA D fragment layout (col = lane&15, row = (lane>>4)*4 + r).
__global__ void combok(const int* __restrict__ ri, const float* __restrict__ tbl,
                       const float* __restrict__ mask, unsigned short* __restrict__ out){
  int g = blockIdx.x*256 + threadIdx.x;
  if (g >= 802816) return;
  int r = g & 3;
  int t = g >> 2;
  int lane = t & 63; t >>= 6;
  int nt = t % 7; t /= 7;
  int mt = t % 7; t /= 7;
  int p = t >> 3, h = t & 7;
  int gi = mt*16 + (lane >> 4)*4 + r; if (gi > 97) gi = 97;
  int j  = nt*16 + (lane & 15);
  float v;
  if (j < 98){
    int wrep = ((p&4)?448:0) + ((p&2)?56:0) + ((p&1)?7:0);
    v = tbl[ri[gi*98 + j]*8 + h] + mask[(size_t)wrep*9604 + gi*98 + j];
  } else {
    v = -30000.f;
  }
  out[g] = f2bf(v);
}

// ---------------- LayerNorm (+optional shift/window map) ----------------
__launch_bounds__(256)
__global__ void lnk(const float* __restrict__ xin, const float* __restrict__ gw, const float* __restrict__ gb,
                    unsigned short* __restrict__ hout, int mode)
{
  int wid = threadIdx.x >> 6, lane = threadIdx.x & 63;
  int tok = blockIdx.x*4 + wid;
  int src;
  if (mode == 0){
    int w = tok / 98, n = tok % 98;
    int b = w >> 9, rr = w & 511;
    int di = rr >> 6, hi = (rr >> 3) & 7, wi = rr & 7;
    int d2 = n / 49, n2 = n % 49, h2 = n2 / 7, w2 = n2 % 7;
    int sd = (di*2 + d2 + 1) & 15;
    int sh = hi*7 + h2 + 3; if (sh >= 56) sh -= 56;
    int sw = wi*7 + w2 + 3; if (sw >= 56) sw -= 56;
    src = ((b*16 + sd)*56 + sh)*56 + sw;
  } else {
    src = tok;
  }
  float4 v = *(const float4*)(xin + (size_t)src*256 + lane*4);
  float s  = v.x + v.y + v.z + v.w;
  float s2 = v.x*v.x + v.y*v.y + v.z*v.z + v.w*v.w;
  #pragma unroll
  for (int off = 1; off < 64; off <<= 1){
    s  += __shfl_xor(s, off);
    s2 += __shfl_xor(s2, off);
  }
  float mean = s * (1.f/256.f);
  float var  = s2 * (1.f/256.f) - mean*mean;
  float rstd = rsqrtf(var + 1e-5f);
  int c = lane*4;
  float4 wv = *(const float4*)(gw + c);
  float4 bv = *(const float4*)(gb + c);
  unsigned int p0 = (unsigned int)f2bf((v.x-mean)*rstd*wv.x + bv.x)
                  | ((unsigned int)f2bf((v.y-mean)*rstd*wv.y + bv.y) << 16);
  unsigned int p1 = (unsigned int)f2bf((v.z-mean)*rstd*wv.z + bv.z)
                  | ((unsigned int)f2bf((v.w-mean)*rstd*wv.w + bv.w) << 16);
  uint2 pk; pk.x = p0; pk.y = p1;
  *(uint2*)(hout + (size_t)tok*256 + c) = pk;
}

// ---------------- bf16 MFMA GEMM: C[M,N] = A[M,K] * Bw[N,K]^T + bias ----------------
// XCD-chunked bijective block swizzle; T2 LDS XOR-swizzle:
//   storage slot(row, kc8) = kc8 ^ ((row>>1)&3)  (staged via pre-swizzled GLOBAL src,
//   LDS dest linear per global_load_lds constraint; ds_read applies same XOR).
// EPI 0: qkv plain [row][768] (+q scale on cols<256)
// EPI 1: proj + unwindow/unroll + residual
// EPI 2: fc1 + GELU(erf) -> bf16           EPI 3: fc2 accumulate into d_out
template<int EPI>
__launch_bounds__(256, 2)
__global__ void gemmk(const unsigned short* __restrict__ A, const unsigned short* __restrict__ Bw,
                      const float* __restrict__ bias, int K, int nbx,
                      unsigned short* __restrict__ outb, const float* __restrict__ xres,
                      float* __restrict__ outf, int moff)
{
  __shared__ unsigned short As[128*32];
  __shared__ unsigned short Bs[128*32];
  int tid = threadIdx.x;
  int wid = tid >> 6, lane = tid & 63, l16 = lane & 15, lk = lane >> 4;
  int wm = wid >> 1, wn = wid & 1;
  int cpx = gridDim.x >> 3;
  int swb = (blockIdx.x & 7)*cpx + (blockIdx.x >> 3);
  int mblk = swb / nbx, nblk = swb % nbx;
  const unsigned short* Ab = A  + (size_t)mblk*128*K;
  const unsigned short* Bb = Bw + (size_t)nblk*128*K;
  int rA = tid >> 2;
  int kcA = (((tid & 3) ^ ((tid >> 3) & 3)))*8;   // pre-swizzled global k-slot
  int sx = (l16 >> 1) & 3;                        // read-side XOR factor

  f32x4 acc[4][4];
  #pragma unroll
  for (int i = 0; i < 4; i++)
    #pragma unroll
    for (int j = 0; j < 4; j++)
      acc[i][j] = (f32x4){0.f,0.f,0.f,0.f};

  for (int ks = 0; ks < K; ks += 32){
    __syncthreads();
    GLDS16(Ab + (size_t)rA*K      + ks + kcA, &As[wid*512]);
    GLDS16(Ab + (size_t)(rA+64)*K + ks + kcA, &As[2048 + wid*512]);
    GLDS16(Bb + (size_t)rA*K      + ks + kcA, &Bs[wid*512]);
    GLDS16(Bb + (size_t)(rA+64)*K + ks + kcA, &Bs[2048 + wid*512]);
    __syncthreads();
    bf16x8 af[4], bfr[4];
    #pragma unroll
    for (int mi = 0; mi < 4; mi++) af[mi]  = *(const bf16x8*)&As[(wm*64 + mi*16 + l16)*32 + (lk ^ sx)*8];
    #pragma unroll
    for (int ni = 0; ni < 4; ni++) bfr[ni] = *(const bf16x8*)&Bs[(wn*64 + ni*16 + l16)*32 + (lk ^ sx)*8];
    #pragma unroll
    for (int mi = 0; mi < 4; mi++)
      #pragma unroll
      for (int ni = 0; ni < 4; ni++)
        acc[mi][ni] = __builtin_amdgcn_mfma_f32_16x16x32_bf16(af[mi], bfr[ni], acc[mi][ni], 0, 0, 0);
  }

  int rowb = mblk*128 + wm*64;
  int colb = nblk*128 + wn*64;
  #pragma unroll
  for (int mi = 0; mi < 4; mi++){
    #pragma unroll
    for (int r = 0; r < 4; r++){
      int row = rowb + mi*16 + lk*4 + r;
      if constexpr (EPI == 0){
        #pragma unroll
        for (int ni = 0; ni < 4; ni++){
          int col = colb + ni*16 + l16;
          float v = acc[mi][ni][r] + bias[col];
          if (col < 256) v *= 0.17677669529663687f;
          outb[(size_t)row*768 + col] = f2bf(v);
        }
      } else if constexpr (EPI == 1){
        int w = row / 98, n = row % 98;
        int b = w >> 9, rr = w & 511;
        int di = rr >> 6, hi = (rr >> 3) & 7, wi = rr & 7;
        int d2 = n / 49, n2 = n % 49, h2 = n2 / 7, w2 = n2 % 7;
        int sd = (di*2 + d2 + 1) & 15;
        int sh = hi*7 + h2 + 3; if (sh >= 56) sh -= 56;
        int sw = wi*7 + w2 + 3; if (sw >= 56) sw -= 56;
        size_t tnat = (((size_t)b*16 + sd)*56 + sh)*56 + sw;
        #pragma unroll
        for (int ni = 0; ni < 4; ni++){
          int col = colb + ni*16 + l16;
          float v = acc[mi][ni][r] + bias[col];
          outf[tnat*256 + col] = xres[tnat*256 + col] + v;
        }
      } else if constexpr (EPI == 2){
        #pragma unroll
        for (int ni = 0; ni < 4; ni++){
          int col = colb + ni*16 + l16;
          float v = acc[mi][ni][r] + bias[col];
          float gl = v * 0.5f * (1.f + erff(v * 0.70710678118654752f));
          outb[(size_t)row*1024 + col] = f2bf(gl);
        }
      } else {
        #pragma unroll
        for (int ni = 0; ni < 4; ni++){
          int col = colb + ni*16 + l16;
          float v = acc[mi][ni][r] + bias[col];
          outf[((size_t)(moff + row))*256 + col] += v;
        }
      }
    }
  }
}

// ---------------- fused window attention ----------------
// One WAVE owns one (window, head), iterates all 7 m-tiles.
// qkv in plain [row][768] (q: cols h*32.., k: +256, v: +512).
// V gathered once per wave as e-pairs (u32 loads); combo enters as MFMA C-init
// (bit-unpack only, no adds); packed u32 output stores.
__launch_bounds__(256)
__global__ void attnk(const unsigned short* __restrict__ qkv, const unsigned short* __restrict__ comboX,
                      unsigned short* __restrict__ obuf)
{
  __shared__ unsigned short P[4][16*136];   // stride 136 breaks the 256B-stride bank conflict
  int tid = threadIdx.x, wid = tid >> 6, lane = tid & 63, l16 = lane & 15, lk = lane >> 4;
  int cpx = gridDim.x >> 3;
  int swb = (blockIdx.x & 7)*cpx + (blockIdx.x >> 3);
  int task = swb*4 + wid;                   // 2048 blocks * 4 waves = 8192 (w,h) tasks
  int w = task >> 3, h = task & 7;
  int rr = w & 511;
  int pat = (((rr>>6)==7)?4:0) | ((((rr>>3)&7)==7)?2:0) | (((rr&7)==7)?1:0);
  const unsigned short* cb = comboX + (size_t)(pat*8 + h)*12544;   // 7mt*7nt*256
  const unsigned short* base = qkv + (size_t)w*98*768 + h*32;      // q cols; k +256; v +512

  // V fragments (transposed gather, e-pair order) once per wave
  bf16x8 v0[4], v1[4];
  #pragma unroll
  for (int kcc = 0; kcc < 4; kcc++){
    #pragma unroll
    for (int j = 0; j < 8; j++){
      int k = kcc*32 + lk*8 + j; if (k > 97) k = 97;   // P is zero past col 97
      unsigned int u = *(const unsigned int*)(base + (size_t)k*768 + 512 + 2*l16);
      v0[kcc][j] = (short)(u & 0xffff);
      v1[kcc][j] = (short)(u >> 16);
    }
  }

  unsigned short* Pw = &P[wid][0];
  { int rp = lane >> 2, cc = 112 + (lane & 3)*4;
    *(uint2*)&Pw[rp*136 + cc] = make_uint2(0u, 0u); }   // zero pad cols 112..127 (never rewritten)

  for (int mt = 0; mt < 7; mt++){
    int qrow = mt*16 + l16; if (qrow > 97) qrow = 97;
    bf16x8 qa = *(const bf16x8*)(base + (size_t)qrow*768 + lk*8);

    const unsigned short* cm = cb + mt*1792;
    f32x4 s[7];
    #pragma unroll
    for (int nt = 0; nt < 7; nt++){
      int kc = nt*16 + l16; if (kc > 97) kc = 97;
      bf16x8 kf = *(const bf16x8*)(base + (size_t)kc*768 + 256 + lk*8);
      uint2 c2 = *(const uint2*)(cm + (nt*64 + lane)*4);
      f32x4 ci;
      ci[0] = __uint_as_float(c2.x << 16);
      ci[1] = __uint_as_float(c2.x & 0xffff0000u);
      ci[2] = __uint_as_float(c2.y << 16);
      ci[3] = __uint_as_float(c2.y & 0xffff0000u);
      s[nt] = __builtin_amdgcn_mfma_f32_16x16x32_bf16(qa, kf, ci, 0, 0, 0);
    }

    float mx[4] = {-3e38f,-3e38f,-3e38f,-3e38f};
    #pragma unroll
    for (int nt = 0; nt < 7; nt++){
      mx[0] = fmaxf(mx[0], s[nt][0]); mx[1] = fmaxf(mx[1], s[nt][1]);
      mx[2] = fmaxf(mx[2], s[nt][2]); mx[3] = fmaxf(mx[3], s[nt][3]);
    }
    #pragma unroll
    for (int r = 0; r < 4; r++){
      #pragma unroll
      for (int off = 1; off < 16; off <<= 1) mx[r] = fmaxf(mx[r], __shfl_xor(mx[r], off));
    }
    float sm[4] = {0.f,0.f,0.f,0.f};
    #pragma unroll
    for (int r = 0; r < 4; r++){
      #pragma unroll
      for (int nt = 0; nt < 7; nt++){
        float e = __expf(s[nt][r] - mx[r]);
        s[nt][r] = e; sm[r] += e;
      }
    }
    #pragma unroll
    for (int r = 0; r < 4; r++){
      #pragma unroll
      for (int off = 1; off < 16; off <<= 1) sm[r] += __shfl_xor(sm[r], off);
      sm[r] = 1.f / sm[r];
    }

    #pragma unroll
    for (int r = 0; r < 4; r++)
      #pragma unroll
      for (int nt = 0; nt < 7; nt++)
        Pw[(lk*4 + r)*136 + nt*16 + l16] = f2bf(s[nt][r]*sm[r]);

    f32x4 o0 = (f32x4){0.f,0.f,0.f,0.f}, o1 = (f32x4){0.f,0.f,0.f,0.f};
    #pragma unroll
    for (int kcc = 0; kcc < 4; kcc++){
      bf16x8 pa = *(const bf16x8*)&Pw[l16*136 + kcc*32 + lk*8];
      __builtin_amdgcn_s_setprio(1);
      o0 = __builtin_amdgcn_mfma_f32_16x16x32_bf16(pa, v0[kcc], o0, 0, 0, 0);
      o1 = __builtin_amdgcn_mfma_f32_16x16x32_bf16(pa, v1[kcc], o1, 0, 0, 0);
      __builtin_amdgcn_s_setprio(0);
    }
    #pragma unroll
    for (int r = 0; r < 4; r++){
      int n = mt*16 + lk*4 + r;
      if (n < 98){
        unsigned int pk = (unsigned int)f2bf(o0[r]) | ((unsigned int)f2bf(o1[r]) << 16);
        *(unsigned int*)(obuf + ((size_t)w*98 + n)*256 + h*32 + 2*l16) = pk;
      }
    }
  }
}

extern "C" void kernel_launch(void* const* d_in, const int* in_sizes, int n_in,
                              void* d_out, int out_size, void* d_ws, size_t ws_size,
                              hipStream_t stream)
{
  const float* x     = (const float*)d_in[0];
  const float* maskm = (const float*)d_in[1];
  const int*   ri    = (const int*)d_in[2];
  const float* tbl   = (const float*)d_in[3];
  const float* n1w   = (const float*)d_in[4];
  const float* n1b   = (const float*)d_in[5];
  const float* qkvw  = (const float*)d_in[6];
  const float* qkvbv = (const float*)d_in[7];
  const float* projw = (const float*)d_in[8];
  const float* projb = (const float*)d_in[9];
  const float* n2w   = (const float*)d_in[10];
  const float* n2b   = (const float*)d_in[11];
  const float* fc1w  = (const float*)d_in[12];
  const float* fc1b  = (const float*)d_in[13];
  const float* fc2w  = (const float*)d_in[14];
  const float* fc2b  = (const float*)d_in[15];
  float* dout = (float*)d_out;
  char* ws = (char*)d_ws;

  // ---- part-1 layout (peak 207.52 MB, under proven 207.62) ----
  unsigned short* qkvB  = (unsigned short*)(ws + 0);           // 100352*768 bf16 = 154,140,672 B
  unsigned short* hb    = (unsigned short*)(ws + 154140672);   // 100352*256 bf16 (LN1 out, then attn out)
  unsigned short* wq    = (unsigned short*)(ws + 205520896);   // 768*256 bf16
  unsigned short* comboX= (unsigned short*)(ws + 205914112);   // 802816 bf16 = 1,605,632 B
  unsigned short* wp    = (unsigned short*)(ws + 0);           // 256*256 bf16, created AFTER attnk (qkv dead)
  // ---- part-2 layout (inside dead qkvB/hb regions), 2 M-chunks of 50176 rows ----
  unsigned short* h2 = (unsigned short*)(ws + 0);              // 100352*256 bf16 = 51,380,224 B
  unsigned short* g  = (unsigned short*)(ws + 51380224);       // 50176*1024 bf16 = 102,760,448 B
  unsigned short* w1 = (unsigned short*)(ws + 154140672);      // 1024*256 bf16
  unsigned short* w2 = (unsigned short*)(ws + 154664960);      // 256*1024 bf16 -> end 155,189,248

  cvtk<<<768, 256, 0, stream>>>(qkvw, wq, 196608);
  combok<<<3136, 256, 0, stream>>>(ri, tbl, maskm, comboX);

  lnk<<<25088, 256, 0, stream>>>(x, n1w, n1b, hb, 0);                                      // LN1+shift+window
  gemmk<0><<<784*6, 256, 0, stream>>>(hb, wq, qkvbv, 256, 6, qkvB, nullptr, nullptr, 0);   // qkv
  attnk<<<2048, 256, 0, stream>>>(qkvB, comboX, hb);                                       // attention
  cvtk<<<256, 256, 0, stream>>>(projw, wp, 65536);                                         // into dead q space
  gemmk<1><<<784*2, 256, 0, stream>>>(hb, wp, projb, 256, 2, nullptr, x, dout, 0);         // proj+residual

  cvtk<<<1024, 256, 0, stream>>>(fc1w, w1, 262144);   // into dead hb space
  cvtk<<<1024, 256, 0, stream>>>(fc2w, w2, 262144);
  lnk<<<25088, 256, 0, stream>>>(dout, n2w, n2b, h2, 1);                                   // LN2
  for (int c = 0; c < 2; c++){
    gemmk<2><<<392*8, 256, 0, stream>>>(h2 + (size_t)c*50176*256, w1, fc1b, 256, 8, g, nullptr, nullptr, 0);
    gemmk<3><<<392*2, 256, 0, stream>>>(g, w2, fc2b, 1024, 2, nullptr, nullptr, dout, c*50176);
  }
}

// Round 7
// 485.747 us; speedup vs baseline: 1.5700x; 1.0031x over previous
//
#include <hip/hip_runtime.h>
#include <hip/hip_bf16.h>

typedef __attribute__((ext_vector_type(8))) short bf16x8;
typedef __attribute__((ext_vector_type(4))) float f32x4;

__device__ __forceinline__ unsigned short f2bf(float f){
  __hip_bfloat16 h = __float2bfloat16(f);
  return *reinterpret_cast<unsigned short*>(&h);
}

#define GLDS16(gptr, lptr) \
  __builtin_amdgcn_global_load_lds((const __attribute__((address_space(1))) unsigned int*)(gptr), \
                                   (__attribute__((address_space(3))) unsigned int*)(lptr), 16, 0, 0)

// ---------------- small prep kernels ----------------
__global__ void cvtk(const float* __restrict__ s, unsigned short* __restrict__ d, int n){
  int i = blockIdx.x*256 + threadIdx.x;
  if (i < n) d[i] = f2bf(s[i]);
}

// comboX[pat][h][mt][nt][lane][r] = rel_bias + mask_pattern, bf16, pre-permuted to the
// exact 16x16x32 MFMA D fragment layout (col = lane&15, row = (lane>>4)*4 + r).
__global__ void combok(const int* __restrict__ ri, const float* __restrict__ tbl,
                       const float* __restrict__ mask, unsigned short* __restrict__ out){
  int g = blockIdx.x*256 + threadIdx.x;
  if (g >= 802816) return;
  int r = g & 3;
  int t = g >> 2;
  int lane = t & 63; t >>= 6;
  int nt = t % 7; t /= 7;
  int mt = t % 7; t /= 7;
  int p = t >> 3, h = t & 7;
  int gi = mt*16 + (lane >> 4)*4 + r; if (gi > 97) gi = 97;
  int j  = nt*16 + (lane & 15);
  float v;
  if (j < 98){
    int wrep = ((p&4)?448:0) + ((p&2)?56:0) + ((p&1)?7:0);
    v = tbl[ri[gi*98 + j]*8 + h] + mask[(size_t)wrep*9604 + gi*98 + j];
  } else {
    v = -30000.f;
  }
  out[g] = f2bf(v);
}

// ---------------- LayerNorm (+optional shift/window map) ----------------
__launch_bounds__(256)
__global__ void lnk(const float* __restrict__ xin, const float* __restrict__ gw, const float* __restrict__ gb,
                    unsigned short* __restrict__ hout, int mode)
{
  int wid = threadIdx.x >> 6, lane = threadIdx.x & 63;
  int tok = blockIdx.x*4 + wid;
  int src;
  if (mode == 0){
    int w = tok / 98, n = tok % 98;
    int b = w >> 9, rr = w & 511;
    int di = rr >> 6, hi = (rr >> 3) & 7, wi = rr & 7;
    int d2 = n / 49, n2 = n % 49, h2 = n2 / 7, w2 = n2 % 7;
    int sd = (di*2 + d2 + 1) & 15;
    int sh = hi*7 + h2 + 3; if (sh >= 56) sh -= 56;
    int sw = wi*7 + w2 + 3; if (sw >= 56) sw -= 56;
    src = ((b*16 + sd)*56 + sh)*56 + sw;
  } else {
    src = tok;
  }
  float4 v = *(const float4*)(xin + (size_t)src*256 + lane*4);
  float s  = v.x + v.y + v.z + v.w;
  float s2 = v.x*v.x + v.y*v.y + v.z*v.z + v.w*v.w;
  #pragma unroll
  for (int off = 1; off < 64; off <<= 1){
    s  += __shfl_xor(s, off);
    s2 += __shfl_xor(s2, off);
  }
  float mean = s * (1.f/256.f);
  float var  = s2 * (1.f/256.f) - mean*mean;
  float rstd = rsqrtf(var + 1e-5f);
  int c = lane*4;
  float4 wv = *(const float4*)(gw + c);
  float4 bv = *(const float4*)(gb + c);
  unsigned int p0 = (unsigned int)f2bf((v.x-mean)*rstd*wv.x + bv.x)
                  | ((unsigned int)f2bf((v.y-mean)*rstd*wv.y + bv.y) << 16);
  unsigned int p1 = (unsigned int)f2bf((v.z-mean)*rstd*wv.z + bv.z)
                  | ((unsigned int)f2bf((v.w-mean)*rstd*wv.w + bv.w) << 16);
  uint2 pk; pk.x = p0; pk.y = p1;
  *(uint2*)(hout + (size_t)tok*256 + c) = pk;
}

// ---------------- bf16 MFMA GEMM: C[M,N] = A[M,K] * Bw[N,K]^T + bias ----------------
// XCD-chunked bijective block swizzle; T2 LDS XOR-swizzle (pre-swizzled global src,
// linear LDS dest, XOR on ds_read); 2-phase double-buffered staging (single barrier/K-step).
// EPI 0: qkv plain [row][768] (+q scale on cols<256)
// EPI 1: proj + unwindow/unroll + residual
// EPI 2: fc1 + GELU(erf) -> bf16           EPI 3: fc2 accumulate into d_out
template<int EPI>
__launch_bounds__(256, 4)
__global__ void gemmk(const unsigned short* __restrict__ A, const unsigned short* __restrict__ Bw,
                      const float* __restrict__ bias, int K, int nbx,
                      unsigned short* __restrict__ outb, const float* __restrict__ xres,
                      float* __restrict__ outf, int moff)
{
  __shared__ unsigned short As[2][4096];
  __shared__ unsigned short Bs[2][4096];
  int tid = threadIdx.x;
  int wid = tid >> 6, lane = tid & 63, l16 = lane & 15, lk = lane >> 4;
  int wm = wid >> 1, wn = wid & 1;
  int cpx = gridDim.x >> 3;
  int swb = (blockIdx.x & 7)*cpx + (blockIdx.x >> 3);
  int mblk = swb / nbx, nblk = swb % nbx;
  const unsigned short* Ab = A  + (size_t)mblk*128*K;
  const unsigned short* Bb = Bw + (size_t)nblk*128*K;
  int rA = tid >> 2;
  int kcA = (((tid & 3) ^ ((tid >> 3) & 3)))*8;   // pre-swizzled global k-slot
  int sx = (l16 >> 1) & 3;                        // read-side XOR factor

#define STAGE(bufi, kss) do { \
    GLDS16(Ab + (size_t)rA*K      + (kss) + kcA, &As[bufi][wid*512]); \
    GLDS16(Ab + (size_t)(rA+64)*K + (kss) + kcA, &As[bufi][2048 + wid*512]); \
    GLDS16(Bb + (size_t)rA*K      + (kss) + kcA, &Bs[bufi][wid*512]); \
    GLDS16(Bb + (size_t)(rA+64)*K + (kss) + kcA, &Bs[bufi][2048 + wid*512]); \
  } while(0)

  f32x4 acc[4][4];
  #pragma unroll
  for (int i = 0; i < 4; i++)
    #pragma unroll
    for (int j = 0; j < 4; j++)
      acc[i][j] = (f32x4){0.f,0.f,0.f,0.f};

  STAGE(0, 0);
  __syncthreads();
  int cur = 0;
  for (int ks = 0; ks < K; ks += 32){
    if (ks + 32 < K) STAGE(cur ^ 1, ks + 32);
    bf16x8 af[4], bfr[4];
    #pragma unroll
    for (int mi = 0; mi < 4; mi++) af[mi]  = *(const bf16x8*)&As[cur][(wm*64 + mi*16 + l16)*32 + (lk ^ sx)*8];
    #pragma unroll
    for (int ni = 0; ni < 4; ni++) bfr[ni] = *(const bf16x8*)&Bs[cur][(wn*64 + ni*16 + l16)*32 + (lk ^ sx)*8];
    #pragma unroll
    for (int mi = 0; mi < 4; mi++)
      #pragma unroll
      for (int ni = 0; ni < 4; ni++)
        acc[mi][ni] = __builtin_amdgcn_mfma_f32_16x16x32_bf16(af[mi], bfr[ni], acc[mi][ni], 0, 0, 0);
    __syncthreads();
    cur ^= 1;
  }
#undef STAGE

  int rowb = mblk*128 + wm*64;
  int colb = nblk*128 + wn*64;
  #pragma unroll
  for (int mi = 0; mi < 4; mi++){
    #pragma unroll
    for (int r = 0; r < 4; r++){
      int row = rowb + mi*16 + lk*4 + r;
      if constexpr (EPI == 0){
        #pragma unroll
        for (int ni = 0; ni < 4; ni++){
          int col = colb + ni*16 + l16;
          float v = acc[mi][ni][r] + bias[col];
          if (col < 256) v *= 0.17677669529663687f;
          outb[(size_t)row*768 + col] = f2bf(v);
        }
      } else if constexpr (EPI == 1){
        int w = row / 98, n = row % 98;
        int b = w >> 9, rr = w & 511;
        int di = rr >> 6, hi = (rr >> 3) & 7, wi = rr & 7;
        int d2 = n / 49, n2 = n % 49, h2 = n2 / 7, w2 = n2 % 7;
        int sd = (di*2 + d2 + 1) & 15;
        int sh = hi*7 + h2 + 3; if (sh >= 56) sh -= 56;
        int sw = wi*7 + w2 + 3; if (sw >= 56) sw -= 56;
        size_t tnat = (((size_t)b*16 + sd)*56 + sh)*56 + sw;
        #pragma unroll
        for (int ni = 0; ni < 4; ni++){
          int col = colb + ni*16 + l16;
          float v = acc[mi][ni][r] + bias[col];
          outf[tnat*256 + col] = xres[tnat*256 + col] + v;
        }
      } else if constexpr (EPI == 2){
        #pragma unroll
        for (int ni = 0; ni < 4; ni++){
          int col = colb + ni*16 + l16;
          float v = acc[mi][ni][r] + bias[col];
          float gl = v * 0.5f * (1.f + erff(v * 0.70710678118654752f));
          outb[(size_t)row*1024 + col] = f2bf(gl);
        }
      } else {
        #pragma unroll
        for (int ni = 0; ni < 4; ni++){
          int col = colb + ni*16 + l16;
          float v = acc[mi][ni][r] + bias[col];
          outf[((size_t)(moff + row))*256 + col] += v;
        }
      }
    }
  }
}

// ---------------- fused window attention ----------------
// One WAVE owns one (window, head), iterates all 7 m-tiles.
// K fragments hoisted to registers (mt-invariant); V gathered once as e-pairs;
// combo enters as MFMA C-init; TILE-wide softmax max (valid: softmax is invariant
// to any per-row constant; one max per 16-row tile, 6-step wave reduce);
// row sums via a 3rd MFMA accumulator with all-ones B (lands in o-register layout);
// normalization deferred to the epilogue (rcp + 2 muls per row).
__launch_bounds__(256)
__global__ void attnk(const unsigned short* __restrict__ qkv, const unsigned short* __restrict__ comboX,
                      unsigned short* __restrict__ obuf)
{
  __shared__ unsigned short P[4][16*136];   // stride 136 breaks the 256B-stride bank conflict
  int tid = threadIdx.x, wid = tid >> 6, lane = tid & 63, l16 = lane & 15, lk = lane >> 4;
  int cpx = gridDim.x >> 3;
  int swb = (blockIdx.x & 7)*cpx + (blockIdx.x >> 3);
  int task = swb*4 + wid;                   // 2048 blocks * 4 waves = 8192 (w,h) tasks
  int w = task >> 3, h = task & 7;
  int rr = w & 511;
  int pat = (((rr>>6)==7)?4:0) | ((((rr>>3)&7)==7)?2:0) | (((rr&7)==7)?1:0);
  const unsigned short* cb = comboX + (size_t)(pat*8 + h)*12544;   // 7mt*7nt*256
  const unsigned short* base = qkv + (size_t)w*98*768 + h*32;      // q cols; k +256; v +512

  // K fragments once per wave (mt-invariant)
  bf16x8 kfr[7];
  #pragma unroll
  for (int nt = 0; nt < 7; nt++){
    int kc = nt*16 + l16; if (kc > 97) kc = 97;
    kfr[nt] = *(const bf16x8*)(base + (size_t)kc*768 + 256 + lk*8);
  }
  // V fragments (transposed gather, e-pair order) once per wave
  bf16x8 v0[4], v1[4];
  #pragma unroll
  for (int kcc = 0; kcc < 4; kcc++){
    #pragma unroll
    for (int j = 0; j < 8; j++){
      int k = kcc*32 + lk*8 + j; if (k > 97) k = 97;   // P is zero past col 97
      unsigned int u = *(const unsigned int*)(base + (size_t)k*768 + 512 + 2*l16);
      v0[kcc][j] = (short)(u & 0xffff);
      v1[kcc][j] = (short)(u >> 16);
    }
  }
  bf16x8 vones;
  #pragma unroll
  for (int j = 0; j < 8; j++) vones[j] = (short)0x3F80;   // bf16 1.0

  unsigned short* Pw = &P[wid][0];
  { int rp = lane >> 2, cc = 112 + (lane & 3)*4;
    *(uint2*)&Pw[rp*136 + cc] = make_uint2(0u, 0u); }   // zero pad cols 112..127 (never rewritten)

  for (int mt = 0; mt < 7; mt++){
    int qrow = mt*16 + l16; if (qrow > 97) qrow = 97;
    bf16x8 qa = *(const bf16x8*)(base + (size_t)qrow*768 + lk*8);

    const unsigned short* cm = cb + mt*1792;
    f32x4 s[7];
    #pragma unroll
    for (int nt = 0; nt < 7; nt++){
      uint2 c2 = *(const uint2*)(cm + (nt*64 + lane)*4);
      f32x4 ci;
      ci[0] = __uint_as_float(c2.x << 16);
      ci[1] = __uint_as_float(c2.x & 0xffff0000u);
      ci[2] = __uint_as_float(c2.y << 16);
      ci[3] = __uint_as_float(c2.y & 0xffff0000u);
      s[nt] = __builtin_amdgcn_mfma_f32_16x16x32_bf16(qa, kfr[nt], ci, 0, 0, 0);
    }

    float mx[4] = {-3e38f,-3e38f,-3e38f,-3e38f};
    #pragma unroll
    for (int nt = 0; nt < 7; nt++){
      mx[0] = fmaxf(mx[0], s[nt][0]); mx[1] = fmaxf(mx[1], s[nt][1]);
      mx[2] = fmaxf(mx[2], s[nt][2]); mx[3] = fmaxf(mx[3], s[nt][3]);
    }
    float mxa = fmaxf(fmaxf(mx[0], mx[1]), fmaxf(mx[2], mx[3]));
    #pragma unroll
    for (int off = 1; off < 64; off <<= 1) mxa = fmaxf(mxa, __shfl_xor(mxa, off));

    #pragma unroll
    for (int r = 0; r < 4; r++)
      #pragma unroll
      for (int nt = 0; nt < 7; nt++)
        Pw[(lk*4 + r)*136 + nt*16 + l16] = f2bf(__expf(s[nt][r] - mxa));

    f32x4 o0 = (f32x4){0.f,0.f,0.f,0.f}, o1 = (f32x4){0.f,0.f,0.f,0.f};
    f32x4 os = (f32x4){0.f,0.f,0.f,0.f};
    #pragma unroll
    for (int kcc = 0; kcc < 4; kcc++){
      bf16x8 pa = *(const bf16x8*)&Pw[l16*136 + kcc*32 + lk*8];
      __builtin_amdgcn_s_setprio(1);
      o0 = __builtin_amdgcn_mfma_f32_16x16x32_bf16(pa, v0[kcc], o0, 0, 0, 0);
      o1 = __builtin_amdgcn_mfma_f32_16x16x32_bf16(pa, v1[kcc], o1, 0, 0, 0);
      os = __builtin_amdgcn_mfma_f32_16x16x32_bf16(pa, vones,   os, 0, 0, 0);
      __builtin_amdgcn_s_setprio(0);
    }
    #pragma unroll
    for (int r = 0; r < 4; r++){
      int n = mt*16 + lk*4 + r;
      if (n < 98){
        float inv = __builtin_amdgcn_rcpf(os[r]);
        unsigned int pk = (unsigned int)f2bf(o0[r]*inv) | ((unsigned int)f2bf(o1[r]*inv) << 16);
        *(unsigned int*)(obuf + ((size_t)w*98 + n)*256 + h*32 + 2*l16) = pk;
      }
    }
  }
}

extern "C" void kernel_launch(void* const* d_in, const int* in_sizes, int n_in,
                              void* d_out, int out_size, void* d_ws, size_t ws_size,
                              hipStream_t stream)
{
  const float* x     = (const float*)d_in[0];
  const float* maskm = (const float*)d_in[1];
  const int*   ri    = (const int*)d_in[2];
  const float* tbl   = (const float*)d_in[3];
  const float* n1w   = (const float*)d_in[4];
  const float* n1b   = (const float*)d_in[5];
  const float* qkvw  = (const float*)d_in[6];
  const float* qkvbv = (const float*)d_in[7];
  const float* projw = (const float*)d_in[8];
  const float* projb = (const float*)d_in[9];
  const float* n2w   = (const float*)d_in[10];
  const float* n2b   = (const float*)d_in[11];
  const float* fc1w  = (const float*)d_in[12];
  const float* fc1b  = (const float*)d_in[13];
  const float* fc2w  = (const float*)d_in[14];
  const float* fc2b  = (const float*)d_in[15];
  float* dout = (float*)d_out;
  char* ws = (char*)d_ws;

  // ---- part-1 layout (peak 207.52 MB, under proven 207.62) ----
  unsigned short* qkvB  = (unsigned short*)(ws + 0);           // 100352*768 bf16 = 154,140,672 B
  unsigned short* hb    = (unsigned short*)(ws + 154140672);   // 100352*256 bf16 (LN1 out, then attn out)
  unsigned short* wq    = (unsigned short*)(ws + 205520896);   // 768*256 bf16
  unsigned short* comboX= (unsigned short*)(ws + 205914112);   // 802816 bf16 = 1,605,632 B
  unsigned short* wp    = (unsigned short*)(ws + 0);           // 256*256 bf16, created AFTER attnk (qkv dead)
  // ---- part-2 layout (inside dead qkvB/hb regions), 2 M-chunks of 50176 rows ----
  unsigned short* h2 = (unsigned short*)(ws + 0);              // 100352*256 bf16 = 51,380,224 B
  unsigned short* g  = (unsigned short*)(ws + 51380224);       // 50176*1024 bf16 = 102,760,448 B
  unsigned short* w1 = (unsigned short*)(ws + 154140672);      // 1024*256 bf16
  unsigned short* w2 = (unsigned short*)(ws + 154664960);      // 256*1024 bf16 -> end 155,189,248

  cvtk<<<768, 256, 0, stream>>>(qkvw, wq, 196608);
  combok<<<3136, 256, 0, stream>>>(ri, tbl, maskm, comboX);

  lnk<<<25088, 256, 0, stream>>>(x, n1w, n1b, hb, 0);                                      // LN1+shift+window
  gemmk<0><<<784*6, 256, 0, stream>>>(hb, wq, qkvbv, 256, 6, qkvB, nullptr, nullptr, 0);   // qkv
  attnk<<<2048, 256, 0, stream>>>(qkvB, comboX, hb);                                       // attention
  cvtk<<<256, 256, 0, stream>>>(projw, wp, 65536);                                         // into dead q space
  gemmk<1><<<784*2, 256, 0, stream>>>(hb, wp, projb, 256, 2, nullptr, x, dout, 0);         // proj+residual

  cvtk<<<1024, 256, 0, stream>>>(fc1w, w1, 262144);   // into dead hb space
  cvtk<<<1024, 256, 0, stream>>>(fc2w, w2, 262144);
  lnk<<<25088, 256, 0, stream>>>(dout, n2w, n2b, h2, 1);                                   // LN2
  for (int c = 0; c < 2; c++){
    gemmk<2><<<392*8, 256, 0, stream>>>(h2 + (size_t)c*50176*256, w1, fc1b, 256, 8, g, nullptr, nullptr, 0);
    gemmk<3><<<392*2, 256, 0, stream>>>(g, w2, fc2b, 1024, 2, nullptr, nullptr, dout, c*50176);
  }
}

// Round 8
// 458.337 us; speedup vs baseline: 1.6639x; 1.0598x over previous
//
#include <hip/hip_runtime.h>
#include <hip/hip_bf16.h>

typedef __attribute__((ext_vector_type(8))) short bf16x8;
typedef __attribute__((ext_vector_type(4))) float f32x4;

__device__ __forceinline__ unsigned short f2bf(float f){
  __hip_bfloat16 h = __float2bfloat16(f);
  return *reinterpret_cast<unsigned short*>(&h);
}

#define GLDS16(gptr, lptr) \
  __builtin_amdgcn_global_load_lds((const __attribute__((address_space(1))) unsigned int*)(gptr), \
                                   (__attribute__((address_space(3))) unsigned int*)(lptr), 16, 0, 0)

// ---------------- small prep kernels ----------------
__global__ void cvtk(const float* __restrict__ s, unsigned short* __restrict__ d, int n){
  int i = blockIdx.x*256 + threadIdx.x;
  if (i < n) d[i] = f2bf(s[i]);
}

// two-source conversion (w1 then w2 into adjacent dests)
__global__ void cvt2k(const float* __restrict__ s1, int n1, const float* __restrict__ s2, int n2,
                      unsigned short* __restrict__ d){
  int i = blockIdx.x*256 + threadIdx.x;
  if (i < n1) d[i] = f2bf(s1[i]);
  else if (i < n1 + n2) d[i] = f2bf(s2[i - n1]);
}

// comboX[pat][h][mt][nt][lane][r] = rel_bias + mask_pattern, bf16, pre-permuted to the
// exact 16x16x32 MFMA D fragment layout (col = lane&15, row = (lane>>4)*4 + r).
__global__ void combok(const int* __restrict__ ri, const float* __restrict__ tbl,
                       const float* __restrict__ mask, unsigned short* __restrict__ out){
  int g = blockIdx.x*256 + threadIdx.x;
  if (g >= 802816) return;
  int r = g & 3;
  int t = g >> 2;
  int lane = t & 63; t >>= 6;
  int nt = t % 7; t /= 7;
  int mt = t % 7; t /= 7;
  int p = t >> 3, h = t & 7;
  int gi = mt*16 + (lane >> 4)*4 + r; if (gi > 97) gi = 97;
  int j  = nt*16 + (lane & 15);
  float v;
  if (j < 98){
    int wrep = ((p&4)?448:0) + ((p&2)?56:0) + ((p&1)?7:0);
    v = tbl[ri[gi*98 + j]*8 + h] + mask[(size_t)wrep*9604 + gi*98 + j];
  } else {
    v = -30000.f;
  }
  out[g] = f2bf(v);
}

// ---------------- LayerNorm (+optional shift/window map) ----------------
__launch_bounds__(256)
__global__ void lnk(const float* __restrict__ xin, const float* __restrict__ gw, const float* __restrict__ gb,
                    unsigned short* __restrict__ hout, int mode)
{
  int wid = threadIdx.x >> 6, lane = threadIdx.x & 63;
  int tok = blockIdx.x*4 + wid;
  int src;
  if (mode == 0){
    int w = tok / 98, n = tok % 98;
    int b = w >> 9, rr = w & 511;
    int di = rr >> 6, hi = (rr >> 3) & 7, wi = rr & 7;
    int d2 = n / 49, n2 = n % 49, h2 = n2 / 7, w2 = n2 % 7;
    int sd = (di*2 + d2 + 1) & 15;
    int sh = hi*7 + h2 + 3; if (sh >= 56) sh -= 56;
    int sw = wi*7 + w2 + 3; if (sw >= 56) sw -= 56;
    src = ((b*16 + sd)*56 + sh)*56 + sw;
  } else {
    src = tok;
  }
  float4 v = *(const float4*)(xin + (size_t)src*256 + lane*4);
  float s  = v.x + v.y + v.z + v.w;
  float s2 = v.x*v.x + v.y*v.y + v.z*v.z + v.w*v.w;
  #pragma unroll
  for (int off = 1; off < 64; off <<= 1){
    s  += __shfl_xor(s, off);
    s2 += __shfl_xor(s2, off);
  }
  float mean = s * (1.f/256.f);
  float var  = s2 * (1.f/256.f) - mean*mean;
  float rstd = rsqrtf(var + 1e-5f);
  int c = lane*4;
  float4 wv = *(const float4*)(gw + c);
  float4 bv = *(const float4*)(gb + c);
  unsigned int p0 = (unsigned int)f2bf((v.x-mean)*rstd*wv.x + bv.x)
                  | ((unsigned int)f2bf((v.y-mean)*rstd*wv.y + bv.y) << 16);
  unsigned int p1 = (unsigned int)f2bf((v.z-mean)*rstd*wv.z + bv.z)
                  | ((unsigned int)f2bf((v.w-mean)*rstd*wv.w + bv.w) << 16);
  uint2 pk; pk.x = p0; pk.y = p1;
  *(uint2*)(hout + (size_t)tok*256 + c) = pk;
}

// ---------------- bf16 MFMA GEMM: C[M,N] = A[M,K] * Bw[N,K]^T + bias ----------------
// XCD-chunked bijective block swizzle; T2 LDS XOR-swizzle; 2-phase dbuf staging.
// B-row permutation: MFMA B-tile ni holds weight rows colb + 4*l16 + ni, so each
// lane's 4 ni-values are 4 CONSECUTIVE output columns -> vectorized epilogues
// (uint2 bf16x4 / float4 stores, coalesced 128B per quarter-wave). Output memory
// layout identical to the unpermuted version.
// EPI 0: qkv plain [row][768] (+q scale on cols<256)
// EPI 1: proj + unwindow/unroll + residual
// EPI 2: fc1 + GELU(erf) -> bf16           EPI 3: fc2 accumulate into d_out
template<int EPI>
__launch_bounds__(256, 4)
__global__ void gemmk(const unsigned short* __restrict__ A, const unsigned short* __restrict__ Bw,
                      const float* __restrict__ bias, int K, int nbx,
                      unsigned short* __restrict__ outb, const float* __restrict__ xres,
                      float* __restrict__ outf, int moff)
{
  __shared__ unsigned short As[2][4096];
  __shared__ unsigned short Bs[2][4096];
  int tid = threadIdx.x;
  int wid = tid >> 6, lane = tid & 63, l16 = lane & 15, lk = lane >> 4;
  int wm = wid >> 1, wn = wid & 1;
  int cpx = gridDim.x >> 3;
  int swb = (blockIdx.x & 7)*cpx + (blockIdx.x >> 3);
  int mblk = swb / nbx, nblk = swb % nbx;
  const unsigned short* Ab = A  + (size_t)mblk*128*K;
  const unsigned short* Bb = Bw + (size_t)nblk*128*K;
  int rA = tid >> 2;
  int rB = ((rA & 15) << 2) + ((rA >> 4) & 3);    // B-row permutation (within 64-half)
  int kcA = (((tid & 3) ^ ((tid >> 3) & 3)))*8;   // pre-swizzled global k-slot
  int sx = (l16 >> 1) & 3;                        // read-side XOR factor

#define STAGE(bufi, kss) do { \
    GLDS16(Ab + (size_t)rA*K      + (kss) + kcA, &As[bufi][wid*512]); \
    GLDS16(Ab + (size_t)(rA+64)*K + (kss) + kcA, &As[bufi][2048 + wid*512]); \
    GLDS16(Bb + (size_t)rB*K      + (kss) + kcA, &Bs[bufi][wid*512]); \
    GLDS16(Bb + (size_t)(rB+64)*K + (kss) + kcA, &Bs[bufi][2048 + wid*512]); \
  } while(0)

  f32x4 acc[4][4];
  #pragma unroll
  for (int i = 0; i < 4; i++)
    #pragma unroll
    for (int j = 0; j < 4; j++)
      acc[i][j] = (f32x4){0.f,0.f,0.f,0.f};

  STAGE(0, 0);
  __syncthreads();
  int cur = 0;
  for (int ks = 0; ks < K; ks += 32){
    if (ks + 32 < K) STAGE(cur ^ 1, ks + 32);
    bf16x8 af[4], bfr[4];
    #pragma unroll
    for (int mi = 0; mi < 4; mi++) af[mi]  = *(const bf16x8*)&As[cur][(wm*64 + mi*16 + l16)*32 + (lk ^ sx)*8];
    #pragma unroll
    for (int ni = 0; ni < 4; ni++) bfr[ni] = *(const bf16x8*)&Bs[cur][(wn*64 + ni*16 + l16)*32 + (lk ^ sx)*8];
    #pragma unroll
    for (int mi = 0; mi < 4; mi++)
      #pragma unroll
      for (int ni = 0; ni < 4; ni++)
        acc[mi][ni] = __builtin_amdgcn_mfma_f32_16x16x32_bf16(af[mi], bfr[ni], acc[mi][ni], 0, 0, 0);
    __syncthreads();
    cur ^= 1;
  }
#undef STAGE

  int rowb = mblk*128 + wm*64;
  int colb = nblk*128 + wn*64;
  int c4 = colb + 4*l16;                 // this lane's 4 consecutive output columns
  float4 bv = *(const float4*)(bias + c4);
  #pragma unroll
  for (int mi = 0; mi < 4; mi++){
    #pragma unroll
    for (int r = 0; r < 4; r++){
      int row = rowb + mi*16 + lk*4 + r;
      float v0 = acc[mi][0][r] + bv.x;
      float v1 = acc[mi][1][r] + bv.y;
      float v2 = acc[mi][2][r] + bv.z;
      float v3 = acc[mi][3][r] + bv.w;
      if constexpr (EPI == 0){
        if (colb < 256){
          const float sc = 0.17677669529663687f;
          v0 *= sc; v1 *= sc; v2 *= sc; v3 *= sc;
        }
        uint2 pk;
        pk.x = (unsigned int)f2bf(v0) | ((unsigned int)f2bf(v1) << 16);
        pk.y = (unsigned int)f2bf(v2) | ((unsigned int)f2bf(v3) << 16);
        *(uint2*)(outb + (size_t)row*768 + c4) = pk;
      } else if constexpr (EPI == 1){
        int w = row / 98, n = row % 98;
        int b = w >> 9, rr = w & 511;
        int di = rr >> 6, hi = (rr >> 3) & 7, wi = rr & 7;
        int d2 = n / 49, n2 = n % 49, h2 = n2 / 7, w2 = n2 % 7;
        int sd = (di*2 + d2 + 1) & 15;
        int sh = hi*7 + h2 + 3; if (sh >= 56) sh -= 56;
        int sw = wi*7 + w2 + 3; if (sw >= 56) sw -= 56;
        size_t tnat = (((size_t)b*16 + sd)*56 + sh)*56 + sw;
        float4 xr = *(const float4*)(xres + tnat*256 + c4);
        float4 ov;
        ov.x = xr.x + v0; ov.y = xr.y + v1; ov.z = xr.z + v2; ov.w = xr.w + v3;
        *(float4*)(outf + tnat*256 + c4) = ov;
      } else if constexpr (EPI == 2){
        float g0 = v0 * 0.5f * (1.f + erff(v0 * 0.70710678118654752f));
        float g1 = v1 * 0.5f * (1.f + erff(v1 * 0.70710678118654752f));
        float g2 = v2 * 0.5f * (1.f + erff(v2 * 0.70710678118654752f));
        float g3 = v3 * 0.5f * (1.f + erff(v3 * 0.70710678118654752f));
        uint2 pk;
        pk.x = (unsigned int)f2bf(g0) | ((unsigned int)f2bf(g1) << 16);
        pk.y = (unsigned int)f2bf(g2) | ((unsigned int)f2bf(g3) << 16);
        *(uint2*)(outb + (size_t)row*1024 + c4) = pk;
      } else {
        float* p = outf + (size_t)(moff + row)*256 + c4;
        float4 cu = *(const float4*)p;
        cu.x += v0; cu.y += v1; cu.z += v2; cu.w += v3;
        *(float4*)p = cu;
      }
    }
  }
}

// ---------------- fused window attention ----------------
// One WAVE owns one (window, head), iterates all 7 m-tiles. K/V fragments hoisted
// to registers; combo enters as MFMA C-init; tile-wide softmax max; row sums via a
// 3rd MFMA accumulator (all-ones B); normalization deferred to the epilogue.
__launch_bounds__(256)
__global__ void attnk(const unsigned short* __restrict__ qkv, const unsigned short* __restrict__ comboX,
                      unsigned short* __restrict__ obuf)
{
  __shared__ unsigned short P[4][16*136];   // stride 136 breaks the 256B-stride bank conflict
  int tid = threadIdx.x, wid = tid >> 6, lane = tid & 63, l16 = lane & 15, lk = lane >> 4;
  int cpx = gridDim.x >> 3;
  int swb = (blockIdx.x & 7)*cpx + (blockIdx.x >> 3);
  int task = swb*4 + wid;                   // 2048 blocks * 4 waves = 8192 (w,h) tasks
  int w = task >> 3, h = task & 7;
  int rr = w & 511;
  int pat = (((rr>>6)==7)?4:0) | ((((rr>>3)&7)==7)?2:0) | (((rr&7)==7)?1:0);
  const unsigned short* cb = comboX + (size_t)(pat*8 + h)*12544;   // 7mt*7nt*256
  const unsigned short* base = qkv + (size_t)w*98*768 + h*32;      // q cols; k +256; v +512

  // K fragments once per wave (mt-invariant)
  bf16x8 kfr[7];
  #pragma unroll
  for (int nt = 0; nt < 7; nt++){
    int kc = nt*16 + l16; if (kc > 97) kc = 97;
    kfr[nt] = *(const bf16x8*)(base + (size_t)kc*768 + 256 + lk*8);
  }
  // V fragments (transposed gather, e-pair order) once per wave
  bf16x8 v0[4], v1[4];
  #pragma unroll
  for (int kcc = 0; kcc < 4; kcc++){
    #pragma unroll
    for (int j = 0; j < 8; j++){
      int k = kcc*32 + lk*8 + j; if (k > 97) k = 97;   // P is zero past col 97
      unsigned int u = *(const unsigned int*)(base + (size_t)k*768 + 512 + 2*l16);
      v0[kcc][j] = (short)(u & 0xffff);
      v1[kcc][j] = (short)(u >> 16);
    }
  }
  bf16x8 vones;
  #pragma unroll
  for (int j = 0; j < 8; j++) vones[j] = (short)0x3F80;   // bf16 1.0

  unsigned short* Pw = &P[wid][0];
  { int rp = lane >> 2, cc = 112 + (lane & 3)*4;
    *(uint2*)&Pw[rp*136 + cc] = make_uint2(0u, 0u); }   // zero pad cols 112..127 (never rewritten)

  for (int mt = 0; mt < 7; mt++){
    int qrow = mt*16 + l16; if (qrow > 97) qrow = 97;
    bf16x8 qa = *(const bf16x8*)(base + (size_t)qrow*768 + lk*8);

    const unsigned short* cm = cb + mt*1792;
    f32x4 s[7];
    #pragma unroll
    for (int nt = 0; nt < 7; nt++){
      uint2 c2 = *(const uint2*)(cm + (nt*64 + lane)*4);
      f32x4 ci;
      ci[0] = __uint_as_float(c2.x << 16);
      ci[1] = __uint_as_float(c2.x & 0xffff0000u);
      ci[2] = __uint_as_float(c2.y << 16);
      ci[3] = __uint_as_float(c2.y & 0xffff0000u);
      s[nt] = __builtin_amdgcn_mfma_f32_16x16x32_bf16(qa, kfr[nt], ci, 0, 0, 0);
    }

    float mx[4] = {-3e38f,-3e38f,-3e38f,-3e38f};
    #pragma unroll
    for (int nt = 0; nt < 7; nt++){
      mx[0] = fmaxf(mx[0], s[nt][0]); mx[1] = fmaxf(mx[1], s[nt][1]);
      mx[2] = fmaxf(mx[2], s[nt][2]); mx[3] = fmaxf(mx[3], s[nt][3]);
    }
    float mxa = fmaxf(fmaxf(mx[0], mx[1]), fmaxf(mx[2], mx[3]));
    #pragma unroll
    for (int off = 1; off < 64; off <<= 1) mxa = fmaxf(mxa, __shfl_xor(mxa, off));

    #pragma unroll
    for (int r = 0; r < 4; r++)
      #pragma unroll
      for (int nt = 0; nt < 7; nt++)
        Pw[(lk*4 + r)*136 + nt*16 + l16] = f2bf(__expf(s[nt][r] - mxa));

    f32x4 o0 = (f32x4){0.f,0.f,0.f,0.f}, o1 = (f32x4){0.f,0.f,0.f,0.f};
    f32x4 os = (f32x4){0.f,0.f,0.f,0.f};
    #pragma unroll
    for (int kcc = 0; kcc < 4; kcc++){
      bf16x8 pa = *(const bf16x8*)&Pw[l16*136 + kcc*32 + lk*8];
      __builtin_amdgcn_s_setprio(1);
      o0 = __builtin_amdgcn_mfma_f32_16x16x32_bf16(pa, v0[kcc], o0, 0, 0, 0);
      o1 = __builtin_amdgcn_mfma_f32_16x16x32_bf16(pa, v1[kcc], o1, 0, 0, 0);
      os = __builtin_amdgcn_mfma_f32_16x16x32_bf16(pa, vones,   os, 0, 0, 0);
      __builtin_amdgcn_s_setprio(0);
    }
    #pragma unroll
    for (int r = 0; r < 4; r++){
      int n = mt*16 + lk*4 + r;
      if (n < 98){
        float inv = __builtin_amdgcn_rcpf(os[r]);
        unsigned int pk = (unsigned int)f2bf(o0[r]*inv) | ((unsigned int)f2bf(o1[r]*inv) << 16);
        *(unsigned int*)(obuf + ((size_t)w*98 + n)*256 + h*32 + 2*l16) = pk;
      }
    }
  }
}

extern "C" void kernel_launch(void* const* d_in, const int* in_sizes, int n_in,
                              void* d_out, int out_size, void* d_ws, size_t ws_size,
                              hipStream_t stream)
{
  const float* x     = (const float*)d_in[0];
  const float* maskm = (const float*)d_in[1];
  const int*   ri    = (const int*)d_in[2];
  const float* tbl   = (const float*)d_in[3];
  const float* n1w   = (const float*)d_in[4];
  const float* n1b   = (const float*)d_in[5];
  const float* qkvw  = (const float*)d_in[6];
  const float* qkvbv = (const float*)d_in[7];
  const float* projw = (const float*)d_in[8];
  const float* projb = (const float*)d_in[9];
  const float* n2w   = (const float*)d_in[10];
  const float* n2b   = (const float*)d_in[11];
  const float* fc1w  = (const float*)d_in[12];
  const float* fc1b  = (const float*)d_in[13];
  const float* fc2w  = (const float*)d_in[14];
  const float* fc2b  = (const float*)d_in[15];
  float* dout = (float*)d_out;
  char* ws = (char*)d_ws;

  // ---- part-1 layout (peak 207.52 MB, under proven 207.62) ----
  unsigned short* qkvB  = (unsigned short*)(ws + 0);           // 100352*768 bf16 = 154,140,672 B
  unsigned short* hb    = (unsigned short*)(ws + 154140672);   // 100352*256 bf16 (LN1 out, then attn out)
  unsigned short* wq    = (unsigned short*)(ws + 205520896);   // 768*256 bf16
  unsigned short* comboX= (unsigned short*)(ws + 205914112);   // 802816 bf16 = 1,605,632 B
  unsigned short* wp    = (unsigned short*)(ws + 0);           // 256*256 bf16, created AFTER attnk (qkv dead)
  // ---- part-2 layout (inside dead qkvB/hb regions), 2 M-chunks of 50176 rows ----
  unsigned short* h2 = (unsigned short*)(ws + 0);              // 100352*256 bf16 = 51,380,224 B
  unsigned short* g  = (unsigned short*)(ws + 51380224);       // 50176*1024 bf16 = 102,760,448 B
  unsigned short* w1 = (unsigned short*)(ws + 154140672);      // 1024*256 bf16
  unsigned short* w2 = (unsigned short*)(ws + 154664960);      // 256*1024 bf16 -> end 155,189,248

  cvtk<<<768, 256, 0, stream>>>(qkvw, wq, 196608);
  combok<<<3136, 256, 0, stream>>>(ri, tbl, maskm, comboX);

  lnk<<<25088, 256, 0, stream>>>(x, n1w, n1b, hb, 0);                                      // LN1+shift+window
  gemmk<0><<<784*6, 256, 0, stream>>>(hb, wq, qkvbv, 256, 6, qkvB, nullptr, nullptr, 0);   // qkv
  attnk<<<2048, 256, 0, stream>>>(qkvB, comboX, hb);                                       // attention
  cvtk<<<256, 256, 0, stream>>>(projw, wp, 65536);                                         // into dead q space
  gemmk<1><<<784*2, 256, 0, stream>>>(hb, wp, projb, 256, 2, nullptr, x, dout, 0);         // proj+residual

  cvt2k<<<2048, 256, 0, stream>>>(fc1w, 262144, fc2w, 262144, w1);   // w1+w2 into dead hb space
  lnk<<<25088, 256, 0, stream>>>(dout, n2w, n2b, h2, 1);                                   // LN2
  for (int c = 0; c < 2; c++){
    gemmk<2><<<392*8, 256, 0, stream>>>(h2 + (size_t)c*50176*256, w1, fc1b, 256, 8, g, nullptr, nullptr, 0);
    gemmk<3><<<392*2, 256, 0, stream>>>(g, w2, fc2b, 1024, 2, nullptr, nullptr, dout, c*50176);
  }
}